// Round 1
// baseline (267.086 us; speedup 1.0000x reference)
//
#include <hip/hip_runtime.h>
#include <math.h>

#define BATCH  128
#define CIN    256
#define HWSZ   1024
#define NATT   64
#define TRI    2080
#define PLANES 256

// ---------------- workspace layout (floats) ----------------
// wt   : [CIN][NATT]            off 0         16384
// gate : [BATCH][PLANES]        off 16384     32768
// psum : [BATCH*2][64]          off 49152     16384
// pcov : [BATCH*2][64][64]      off 65536     1048576
// Y    : [BATCH][64][1024]      off 1114112   8388608
static const size_t WT_OFF   = 0;
static const size_t GATE_OFF = 16384;
static const size_t PSUM_OFF = 49152;
static const size_t PCOV_OFF = 65536;
static const size_t Y_OFF    = 1114112;

// ---------------- kernel 0: transpose conv_w ----------------
__global__ void k_transpose_w(const float* __restrict__ w, float* __restrict__ wt){
  for (int idx = threadIdx.x; idx < NATT*CIN; idx += 256){
    int o = idx >> 8;          // /CIN
    int c = idx & (CIN-1);
    wt[c*NATT + o] = w[o*CIN + c];
  }
}

// ---------------- kernel 1: 1x1 conv + BN + ReLU ----------------
// grid: BATCH * (HWSZ/256) = 512 blocks, 256 threads. 1 pixel per thread, 64 outputs.
__global__ __launch_bounds__(256) void k_conv_bn_relu(
    const float* __restrict__ x, const float* __restrict__ wt,
    const float* __restrict__ gam, const float* __restrict__ bet,
    const float* __restrict__ mu,  const float* __restrict__ var,
    float* __restrict__ Y){
  int b = blockIdx.x >> 2;
  int p = ((blockIdx.x & 3) << 8) + threadIdx.x;
  const float* xp = x + ((size_t)b*CIN)*HWSZ + p;
  float acc[NATT];
#pragma unroll
  for (int o=0;o<NATT;o++) acc[o]=0.f;
  for (int c=0;c<CIN;c++){
    float xv = xp[(size_t)c*HWSZ];
    const float* wc = wt + c*NATT;   // wave-uniform address -> s_load broadcast
#pragma unroll
    for (int o=0;o<NATT;o++) acc[o] = fmaf(xv, wc[o], acc[o]);
  }
  float* yp = Y + ((size_t)b*NATT)*HWSZ + p;
#pragma unroll
  for (int o=0;o<NATT;o++){
    float sc = gam[o]*rsqrtf(var[o]+1e-5f);
    float sh = bet[o] - mu[o]*sc;
    float v = fmaf(acc[o], sc, sh);
    yp[(size_t)o*HWSZ] = v>0.f ? v : 0.f;
  }
}

// ---------------- kernel 2: covariance pooling (partial) ----------------
// grid: BATCH*2 blocks (each does 512 of the 1024 M-columns), 256 threads.
// outputs: pcov[blk][64][64] = sum_m y_i y_j (partial), psum[blk][64] = sum_m y_i (partial)
__global__ __launch_bounds__(256) void k_covpool(const float* __restrict__ Y,
    float* __restrict__ pcov, float* __restrict__ psum){
  __shared__ float ys[64][132];       // 128-col tile, padded rows (stride 132 floats)
  __shared__ float psl[64];
  int b = blockIdx.x >> 1, half = blockIdx.x & 1;
  int tid = threadIdx.x;
  if (tid < 64) psl[tid] = 0.f;
  float acc[4][4];
#pragma unroll
  for (int i=0;i<4;i++)
#pragma unroll
    for (int j=0;j<4;j++) acc[i][j]=0.f;
  int ibase = tid >> 4;     // 0..15  rows {ibase+16*ii}
  int jbase = tid & 15;     // 0..15  rows {jbase+16*jj}
  const float* yb = Y + ((size_t)b*NATT)*HWSZ + half*512;

  for (int mt=0; mt<512; mt+=128){
    __syncthreads();
    // stage 64x128 tile (float4, coalesced)
#pragma unroll
    for (int k=0;k<8;k++){
      int q  = tid + (k<<8);
      int r  = q >> 5;
      int cq = q & 31;
      const float4 v = *(const float4*)(yb + (size_t)r*HWSZ + mt + (cq<<2));
      *(float4*)&ys[r][cq<<2] = v;
    }
    __syncthreads();
    // row partial sums (for the mean)
    {
      int r = tid>>2, qt = tid&3;
      float s = 0.f;
      int base = qt<<5;
#pragma unroll
      for (int mm=0;mm<32;mm++) s += ys[r][base+mm];
      s += __shfl_down(s, 2);
      s += __shfl_down(s, 1);
      if (qt==0) psl[r] += s;
    }
    // gram accumulation, float4 along m
    for (int m=0;m<128;m+=4){
      float am[4][4], bm[4][4];
#pragma unroll
      for (int ii=0;ii<4;ii++){
        float4 v = *(const float4*)&ys[ibase+16*ii][m];
        am[ii][0]=v.x; am[ii][1]=v.y; am[ii][2]=v.z; am[ii][3]=v.w;
      }
#pragma unroll
      for (int jj=0;jj<4;jj++){
        float4 v = *(const float4*)&ys[jbase+16*jj][m];
        bm[jj][0]=v.x; bm[jj][1]=v.y; bm[jj][2]=v.z; bm[jj][3]=v.w;
      }
#pragma unroll
      for (int ii=0;ii<4;ii++)
#pragma unroll
        for (int jj=0;jj<4;jj++){
          acc[ii][jj] = fmaf(am[ii][0], bm[jj][0], acc[ii][jj]);
          acc[ii][jj] = fmaf(am[ii][1], bm[jj][1], acc[ii][jj]);
          acc[ii][jj] = fmaf(am[ii][2], bm[jj][2], acc[ii][jj]);
          acc[ii][jj] = fmaf(am[ii][3], bm[jj][3], acc[ii][jj]);
        }
    }
  }
  float* pc = pcov + (size_t)blockIdx.x * (NATT*NATT);
#pragma unroll
  for (int ii=0;ii<4;ii++)
#pragma unroll
    for (int jj=0;jj<4;jj++)
      pc[(ibase+16*ii)*NATT + (jbase+16*jj)] = acc[ii][jj];
  __syncthreads();
  if (tid < 64) psum[(size_t)blockIdx.x*64 + tid] = psl[tid];
}

// ---------------- 64x64 LDS matmul helper (padded stride 68) ----------------
__device__ __forceinline__ void mm64(float (*__restrict__ D)[68],
                                     const float (*__restrict__ L)[68],
                                     const float (*__restrict__ R)[68], int tid){
  int i0 = (tid>>4)<<2;   // 0..60
  int j0 = (tid&15)<<2;   // 0..60
  float acc[4][4];
#pragma unroll
  for (int i=0;i<4;i++)
#pragma unroll
    for (int j=0;j<4;j++) acc[i][j]=0.f;
  for (int k=0;k<64;k+=4){
    float am[4][4], bm[4][4];
#pragma unroll
    for (int ii=0;ii<4;ii++){
      float4 v = *(const float4*)&L[i0+ii][k];
      am[ii][0]=v.x; am[ii][1]=v.y; am[ii][2]=v.z; am[ii][3]=v.w;
    }
#pragma unroll
    for (int kk=0;kk<4;kk++){
      float4 v = *(const float4*)&R[k+kk][j0];
      bm[kk][0]=v.x; bm[kk][1]=v.y; bm[kk][2]=v.z; bm[kk][3]=v.w;
    }
#pragma unroll
    for (int ii=0;ii<4;ii++)
#pragma unroll
      for (int jj=0;jj<4;jj++){
        acc[ii][jj] = fmaf(am[ii][0], bm[0][jj], acc[ii][jj]);
        acc[ii][jj] = fmaf(am[ii][1], bm[1][jj], acc[ii][jj]);
        acc[ii][jj] = fmaf(am[ii][2], bm[2][jj], acc[ii][jj]);
        acc[ii][jj] = fmaf(am[ii][3], bm[3][jj], acc[ii][jj]);
      }
  }
#pragma unroll
  for (int ii=0;ii<4;ii++)
#pragma unroll
    for (int jj=0;jj<4;jj++)
      D[i0+ii][j0+jj] = acc[ii][jj];
}

// ---------------- kernel 3: Newton-Schulz sqrt + triuvec + FC + sigmoid ----------------
// grid: BATCH blocks, 256 threads; everything for one batch lives in LDS.
__global__ __launch_bounds__(256) void k_ns_fc(const float* __restrict__ pcov,
    const float* __restrict__ psum, const float* __restrict__ fcw,
    const float* __restrict__ fcb, float* __restrict__ gate){
  __shared__ float A [64][68];
  __shared__ float T [64][68];
  __shared__ float Y0[64][68];
  __shared__ float Y1[64][68];
  __shared__ float Z0[64][68];
  __shared__ float Z1[64][68];
  __shared__ __align__(16) float vec[TRI];
  __shared__ float meanl[64];
  __shared__ float snorm;
  int b = blockIdx.x, tid = threadIdx.x;
  const float* pc0 = pcov + ((size_t)b*2) * (NATT*NATT);
  const float* pc1 = pc0 + NATT*NATT;
  if (tid < 64)
    meanl[tid] = (psum[(size_t)b*128 + tid] + psum[(size_t)b*128 + 64 + tid]) * (1.f/1024.f);
  __syncthreads();
  // A = cov = E[yy^T] - mu mu^T
  for (int e=tid; e<4096; e+=256){
    int i = e>>6, j = e&63;
    A[i][j] = (pc0[e] + pc1[e]) * (1.f/1024.f) - meanl[i]*meanl[j];
  }
  __syncthreads();
  if (tid == 0){
    float s = 0.f;
    for (int i=0;i<64;i++) s += A[i][i];
    snorm = s;
  }
  __syncthreads();
  float normA = snorm;
  float inv = 1.f/normA;
  // An (in A); T = 0.5*(3I - An); Z0 = T
  for (int e=tid; e<4096; e+=256){
    int i = e>>6, j = e&63;
    float an = A[i][j]*inv;
    A[i][j] = an;
    float t = 0.5f*((i==j?3.f:0.f) - an);
    T[i][j] = t;
    Z0[i][j] = t;
  }
  __syncthreads();
  mm64(Y0, A, T, tid);           // Y = An @ ZY
  __syncthreads();

#define NS_ITER(Yc,Zc,Yn,Zn) \
  mm64(T, Zc, Yc, tid); __syncthreads(); \
  for (int e=tid; e<4096; e+=256){ int i=e>>6, j=e&63; T[i][j] = 0.5f*((i==j?3.f:0.f) - T[i][j]); } \
  __syncthreads(); \
  mm64(Yn, Yc, T, tid); \
  mm64(Zn, T, Zc, tid); \
  __syncthreads();

  NS_ITER(Y0,Z0,Y1,Z1)
  NS_ITER(Y1,Z1,Y0,Z0)
  NS_ITER(Y0,Z0,Y1,Z1)
#undef NS_ITER

  // final: ZY = 0.5 * Y @ (3I - Z@Y), result scaled by sqrt(normA)
  mm64(T, Z1, Y1, tid);
  __syncthreads();
  for (int e=tid; e<4096; e+=256){ int i=e>>6, j=e&63; T[i][j] = (i==j?3.f:0.f) - T[i][j]; }
  __syncthreads();
  mm64(A, Y1, T, tid);
  __syncthreads();
  float scl = 0.5f * sqrtf(normA);
  // triuvec (row-major upper incl diag)
  for (int e=tid; e<4096; e+=256){
    int i = e>>6, j = e&63;
    if (j >= i){
      int t0 = (i*(129 - i)) >> 1;
      vec[t0 + j - i] = A[i][j]*scl;
    }
  }
  __syncthreads();
  // FC + sigmoid: one plane per thread
  {
    int p = tid;
    const float* wr = fcw + (size_t)p*TRI;
    float acc = fcb[p];
    for (int t=0; t<TRI; t+=4){
      float4 wv = *(const float4*)(wr + t);
      float4 vv = *(const float4*)(vec + t);
      acc = fmaf(wv.x, vv.x, acc);
      acc = fmaf(wv.y, vv.y, acc);
      acc = fmaf(wv.z, vv.z, acc);
      acc = fmaf(wv.w, vv.w, acc);
    }
    gate[(size_t)b*PLANES + p] = 1.f/(1.f + expf(-acc));
  }
}

// ---------------- kernel 4: out = x * gate[b,c] ----------------
__global__ __launch_bounds__(256) void k_gate_mul(const float* __restrict__ x,
    const float* __restrict__ gate, float* __restrict__ out){
  size_t i4 = (size_t)blockIdx.x*256 + threadIdx.x;
  size_t e  = i4 << 2;
  int bc = (int)(e >> 10);            // = b*256 + c
  float g = gate[bc];
  float4 v = *(const float4*)(x + e);
  v.x *= g; v.y *= g; v.z *= g; v.w *= g;
  *(float4*)(out + e) = v;
}

extern "C" void kernel_launch(void* const* d_in, const int* in_sizes, int n_in,
                              void* d_out, int out_size, void* d_ws, size_t ws_size,
                              hipStream_t stream) {
  const float* x    = (const float*)d_in[0];
  const float* cw   = (const float*)d_in[1];
  const float* gam  = (const float*)d_in[2];
  const float* bet  = (const float*)d_in[3];
  const float* mu   = (const float*)d_in[4];
  const float* var  = (const float*)d_in[5];
  const float* fcw  = (const float*)d_in[6];
  const float* fcb  = (const float*)d_in[7];
  float* out = (float*)d_out;
  float* ws  = (float*)d_ws;

  float* wt   = ws + WT_OFF;
  float* gate = ws + GATE_OFF;
  float* psum = ws + PSUM_OFF;
  float* pcov = ws + PCOV_OFF;
  float* Y    = ws + Y_OFF;

  k_transpose_w<<<1, 256, 0, stream>>>(cw, wt);
  k_conv_bn_relu<<<BATCH*4, 256, 0, stream>>>(x, wt, gam, bet, mu, var, Y);
  k_covpool<<<BATCH*2, 256, 0, stream>>>(Y, pcov, psum);
  k_ns_fc<<<BATCH, 256, 0, stream>>>(pcov, psum, fcw, fcb, gate);
  k_gate_mul<<<(BATCH*CIN*HWSZ)/1024, 256, 0, stream>>>(x, gate, out);
}

// Round 2
// 235.409 us; speedup vs baseline: 1.1346x; 1.1346x over previous
//
#include <hip/hip_runtime.h>
#include <math.h>

#define BATCH  128
#define CIN    256
#define HWSZ   1024
#define NATT   64
#define TRI    2080
#define PLANES 256

// ---------------- workspace layout (floats) ----------------
static const size_t WT_OFF   = 0;                 // [CIN][NATT]        16384
static const size_t GATE_OFF = 16384;             // [BATCH][PLANES]    32768
static const size_t PSUM_OFF = 49152;             // [BATCH*4][64]      32768
static const size_t PCOV_OFF = 81920;             // [BATCH*4][64][64]  2097152
static const size_t Y_OFF    = 2179072;           // [BATCH][64][1024]  8388608

// ---------------- kernel 0: transpose conv_w ----------------
__global__ void k_transpose_w(const float* __restrict__ w, float* __restrict__ wt){
  for (int idx = threadIdx.x; idx < NATT*CIN; idx += 256){
    int o = idx >> 8;
    int c = idx & (CIN-1);
    wt[c*NATT + o] = w[o*CIN + c];
  }
}

// ---------------- kernel 1: 1x1 conv + BN + ReLU (LDS-tiled GEMM) ----------------
// grid: BATCH*8 (pixel chunks of 128), 256 threads.
// thread: to = tid>>4 (4 outputs), tp = tid&15 (8 pixels: tp*4+{0..3} and 64+tp*4+{0..3})
#define CCH 32
__global__ __launch_bounds__(256) void k_conv_bn_relu(
    const float* __restrict__ x, const float* __restrict__ wt,
    const float* __restrict__ gam, const float* __restrict__ bet,
    const float* __restrict__ mu,  const float* __restrict__ var,
    float* __restrict__ Y){
  __shared__ float xs[CCH][132];
  __shared__ float wsh[CCH][64];
  int b = blockIdx.x >> 3;
  int chunk = blockIdx.x & 7;
  int tid = threadIdx.x;
  int to = tid >> 4;
  int tp = tid & 15;
  const float* xb = x + ((size_t)b*CIN)*HWSZ + chunk*128;
  float acc[4][8];
#pragma unroll
  for (int i=0;i<4;i++)
#pragma unroll
    for (int j=0;j<8;j++) acc[i][j]=0.f;

  for (int c0=0; c0<CIN; c0+=CCH){
    __syncthreads();
    // stage x tile [32][128] (coalesced float4)
#pragma unroll
    for (int k=0;k<4;k++){
      int q = tid + (k<<8);
      int r = q >> 5, col = (q & 31) << 2;
      *(float4*)&xs[r][col] = *(const float4*)(xb + (size_t)(c0+r)*HWSZ + col);
    }
    // stage w tile [32][64]
#pragma unroll
    for (int k=0;k<2;k++){
      int q = tid + (k<<8);
      int r = q >> 4, col = (q & 15) << 2;
      *(float4*)&wsh[r][col] = *(const float4*)(wt + (size_t)(c0+r)*NATT + col);
    }
    __syncthreads();
#pragma unroll 8
    for (int c=0;c<CCH;c++){
      float4 wv = *(const float4*)&wsh[c][to<<2];
      float4 xa = *(const float4*)&xs[c][tp<<2];
      float4 xc = *(const float4*)&xs[c][64 + (tp<<2)];
      float xv[8] = {xa.x,xa.y,xa.z,xa.w,xc.x,xc.y,xc.z,xc.w};
      float wv4[4] = {wv.x,wv.y,wv.z,wv.w};
#pragma unroll
      for (int oo=0;oo<4;oo++)
#pragma unroll
        for (int pp=0;pp<8;pp++)
          acc[oo][pp] = fmaf(wv4[oo], xv[pp], acc[oo][pp]);
    }
  }
  // epilogue: BN + ReLU + store
#pragma unroll
  for (int oo=0;oo<4;oo++){
    int o = (to<<2) + oo;
    float sc = gam[o]*rsqrtf(var[o]+1e-5f);
    float sh = bet[o] - mu[o]*sc;
    float* yp = Y + ((size_t)b*NATT + o)*HWSZ + chunk*128;
    float4 v0, v1;
    v0.x = fmaf(acc[oo][0], sc, sh); v0.y = fmaf(acc[oo][1], sc, sh);
    v0.z = fmaf(acc[oo][2], sc, sh); v0.w = fmaf(acc[oo][3], sc, sh);
    v1.x = fmaf(acc[oo][4], sc, sh); v1.y = fmaf(acc[oo][5], sc, sh);
    v1.z = fmaf(acc[oo][6], sc, sh); v1.w = fmaf(acc[oo][7], sc, sh);
    v0.x = v0.x>0.f?v0.x:0.f; v0.y = v0.y>0.f?v0.y:0.f;
    v0.z = v0.z>0.f?v0.z:0.f; v0.w = v0.w>0.f?v0.w:0.f;
    v1.x = v1.x>0.f?v1.x:0.f; v1.y = v1.y>0.f?v1.y:0.f;
    v1.z = v1.z>0.f?v1.z:0.f; v1.w = v1.w>0.f?v1.w:0.f;
    *(float4*)(yp + (tp<<2)) = v0;
    *(float4*)(yp + 64 + (tp<<2)) = v1;
  }
}

// ---------------- kernel 2: covariance pooling (partial) ----------------
// grid: BATCH*4 (quarters of 256 cols), 256 threads.
// i-rows: consecutive 4 (i0..i0+3); j-rows: strided 16 (jb+16*jj) — both 2-way max.
__global__ __launch_bounds__(256) void k_covpool(const float* __restrict__ Y,
    float* __restrict__ pcov, float* __restrict__ psum){
  __shared__ float ys[64][132];
  __shared__ float psl[64];
  int b = blockIdx.x >> 2, quarter = blockIdx.x & 3;
  int tid = threadIdx.x;
  if (tid < 64) psl[tid] = 0.f;
  float acc[4][4];
#pragma unroll
  for (int i=0;i<4;i++)
#pragma unroll
    for (int j=0;j<4;j++) acc[i][j]=0.f;
  int i0 = (tid >> 4) << 2;
  int jb = tid & 15;
  const float* yb = Y + ((size_t)b*NATT)*HWSZ + quarter*256;

  for (int mt=0; mt<256; mt+=128){
    __syncthreads();
#pragma unroll
    for (int k=0;k<8;k++){
      int q  = tid + (k<<8);
      int r  = q >> 5;
      int cq = (q & 31) << 2;
      *(float4*)&ys[r][cq] = *(const float4*)(yb + (size_t)r*HWSZ + mt + cq);
    }
    __syncthreads();
    {
      int r = tid>>2, qt = tid&3;
      float s = 0.f;
      int base = qt<<5;
#pragma unroll
      for (int mm=0;mm<32;mm++) s += ys[r][base+mm];
      s += __shfl_down(s, 2);
      s += __shfl_down(s, 1);
      if (qt==0) psl[r] += s;
    }
    for (int m=0;m<128;m+=4){
      float am[4][4], bm[4][4];
#pragma unroll
      for (int ii=0;ii<4;ii++){
        float4 v = *(const float4*)&ys[i0+ii][m];
        am[ii][0]=v.x; am[ii][1]=v.y; am[ii][2]=v.z; am[ii][3]=v.w;
      }
#pragma unroll
      for (int jj=0;jj<4;jj++){
        float4 v = *(const float4*)&ys[jb+16*jj][m];
        bm[jj][0]=v.x; bm[jj][1]=v.y; bm[jj][2]=v.z; bm[jj][3]=v.w;
      }
#pragma unroll
      for (int ii=0;ii<4;ii++)
#pragma unroll
        for (int jj=0;jj<4;jj++){
          acc[ii][jj] = fmaf(am[ii][0], bm[jj][0], acc[ii][jj]);
          acc[ii][jj] = fmaf(am[ii][1], bm[jj][1], acc[ii][jj]);
          acc[ii][jj] = fmaf(am[ii][2], bm[jj][2], acc[ii][jj]);
          acc[ii][jj] = fmaf(am[ii][3], bm[jj][3], acc[ii][jj]);
        }
    }
  }
  float* pc = pcov + (size_t)blockIdx.x * (NATT*NATT);
#pragma unroll
  for (int ii=0;ii<4;ii++)
#pragma unroll
    for (int jj=0;jj<4;jj++)
      pc[(i0+ii)*NATT + jb + 16*jj] = acc[ii][jj];
  __syncthreads();
  if (tid < 64) psum[(size_t)blockIdx.x*64 + tid] = psl[tid];
}

// ---------------- 64x64 LDS matmul (512 threads, 4x2 tiles) ----------------
__device__ __forceinline__ void mm64(float (*__restrict__ D)[68],
                                     const float (*__restrict__ L)[68],
                                     const float (*__restrict__ R)[68], int tid){
  int i0 = (tid>>5)<<2;   // 0..60 (consecutive 4 rows)
  int j0 = (tid&31)<<1;   // 0..62 (2 cols)
  float acc[4][2];
#pragma unroll
  for (int i=0;i<4;i++){ acc[i][0]=0.f; acc[i][1]=0.f; }
#pragma unroll 4
  for (int k=0;k<64;k+=4){
    float am[4][4], bm[4][2];
#pragma unroll
    for (int ii=0;ii<4;ii++){
      float4 v = *(const float4*)&L[i0+ii][k];
      am[ii][0]=v.x; am[ii][1]=v.y; am[ii][2]=v.z; am[ii][3]=v.w;
    }
#pragma unroll
    for (int kk=0;kk<4;kk++){
      bm[kk][0] = R[k+kk][j0];
      bm[kk][1] = R[k+kk][j0+1];
    }
#pragma unroll
    for (int ii=0;ii<4;ii++)
#pragma unroll
      for (int jj=0;jj<2;jj++){
        acc[ii][jj] = fmaf(am[ii][0], bm[0][jj], acc[ii][jj]);
        acc[ii][jj] = fmaf(am[ii][1], bm[1][jj], acc[ii][jj]);
        acc[ii][jj] = fmaf(am[ii][2], bm[2][jj], acc[ii][jj]);
        acc[ii][jj] = fmaf(am[ii][3], bm[3][jj], acc[ii][jj]);
      }
  }
#pragma unroll
  for (int ii=0;ii<4;ii++){
    D[i0+ii][j0]   = acc[ii][0];
    D[i0+ii][j0+1] = acc[ii][1];
  }
}

// ---------------- kernel 3: Newton-Schulz + triuvec + FC + sigmoid ----------------
// grid: BATCH blocks, 512 threads.
__global__ __launch_bounds__(512) void k_ns_fc(const float* __restrict__ pcov,
    const float* __restrict__ psum, const float* __restrict__ fcw,
    const float* __restrict__ fcb, float* __restrict__ gate){
  __shared__ float A [64][68];
  __shared__ float T [64][68];
  __shared__ float Y0[64][68];
  __shared__ float Y1[64][68];
  __shared__ float Z0[64][68];
  __shared__ float Z1[64][68];
  __shared__ __align__(16) float vec[TRI];
  __shared__ float meanl[64];
  __shared__ float snorm;
  int b = blockIdx.x, tid = threadIdx.x;
  const float* pc0 = pcov + ((size_t)b*4) * (NATT*NATT);
  if (tid < 64){
    const float* ps = psum + (size_t)b*256;
    meanl[tid] = (ps[tid] + ps[64+tid] + ps[128+tid] + ps[192+tid]) * (1.f/1024.f);
  }
  __syncthreads();
  for (int e=tid; e<4096; e+=512){
    int i = e>>6, j = e&63;
    A[i][j] = (pc0[e] + pc0[4096+e] + pc0[8192+e] + pc0[12288+e]) * (1.f/1024.f)
              - meanl[i]*meanl[j];
  }
  __syncthreads();
  if (tid < 64){
    float s = A[tid][tid];
#pragma unroll
    for (int off=32; off; off>>=1) s += __shfl_down(s, off);
    if (tid==0) snorm = s;
  }
  __syncthreads();
  float normA = snorm;
  float inv = 1.f/normA;
  for (int e=tid; e<4096; e+=512){
    int i = e>>6, j = e&63;
    float an = A[i][j]*inv;
    A[i][j] = an;
    float t = 0.5f*((i==j?3.f:0.f) - an);
    T[i][j] = t;
    Z0[i][j] = t;
  }
  __syncthreads();
  mm64(Y0, A, T, tid);
  __syncthreads();

#define NS_ITER(Yc,Zc,Yn,Zn) \
  mm64(T, Zc, Yc, tid); __syncthreads(); \
  for (int e=tid; e<4096; e+=512){ int i=e>>6, j=e&63; T[i][j] = 0.5f*((i==j?3.f:0.f) - T[i][j]); } \
  __syncthreads(); \
  mm64(Yn, Yc, T, tid); \
  mm64(Zn, T, Zc, tid); \
  __syncthreads();

  NS_ITER(Y0,Z0,Y1,Z1)
  NS_ITER(Y1,Z1,Y0,Z0)
  NS_ITER(Y0,Z0,Y1,Z1)
#undef NS_ITER

  mm64(T, Z1, Y1, tid);
  __syncthreads();
  for (int e=tid; e<4096; e+=512){ int i=e>>6, j=e&63; T[i][j] = (i==j?3.f:0.f) - T[i][j]; }
  __syncthreads();
  mm64(A, Y1, T, tid);
  __syncthreads();
  float scl = 0.5f * sqrtf(normA);
  for (int e=tid; e<4096; e+=512){
    int i = e>>6, j = e&63;
    if (j >= i){
      int t0 = (i*(129 - i)) >> 1;
      vec[t0 + j - i] = A[i][j]*scl;
    }
  }
  __syncthreads();
  // FC + sigmoid: 2 threads per plane
  {
    int p  = tid >> 1;
    int hf = tid & 1;
    const float* wr = fcw + (size_t)p*TRI + hf*1040;
    const float* vr = vec + hf*1040;
    float acc = 0.f;
    for (int t=0; t<1040; t+=4){
      float4 wv = *(const float4*)(wr + t);
      float4 vv = *(const float4*)(vr + t);
      acc = fmaf(wv.x, vv.x, acc);
      acc = fmaf(wv.y, vv.y, acc);
      acc = fmaf(wv.z, vv.z, acc);
      acc = fmaf(wv.w, vv.w, acc);
    }
    acc += __shfl_xor(acc, 1);
    if (hf==0)
      gate[(size_t)b*PLANES + p] = 1.f/(1.f + expf(-(acc + fcb[p])));
  }
}

// ---------------- kernel 4: out = x * gate[b,c] (grid-stride) ----------------
__global__ __launch_bounds__(256) void k_gate_mul(const float* __restrict__ x,
    const float* __restrict__ gate, float* __restrict__ out){
  size_t base = (size_t)blockIdx.x*256 + threadIdx.x;
#pragma unroll
  for (int k=0;k<8;k++){
    size_t i4 = base + (size_t)k*1048576;
    size_t e  = i4 << 2;
    int bc = (int)(e >> 10);
    float g = gate[bc];
    float4 v = *(const float4*)(x + e);
    v.x *= g; v.y *= g; v.z *= g; v.w *= g;
    *(float4*)(out + e) = v;
  }
}

extern "C" void kernel_launch(void* const* d_in, const int* in_sizes, int n_in,
                              void* d_out, int out_size, void* d_ws, size_t ws_size,
                              hipStream_t stream) {
  const float* x    = (const float*)d_in[0];
  const float* cw   = (const float*)d_in[1];
  const float* gam  = (const float*)d_in[2];
  const float* bet  = (const float*)d_in[3];
  const float* mu   = (const float*)d_in[4];
  const float* var  = (const float*)d_in[5];
  const float* fcw  = (const float*)d_in[6];
  const float* fcb  = (const float*)d_in[7];
  float* out = (float*)d_out;
  float* ws  = (float*)d_ws;

  float* wt   = ws + WT_OFF;
  float* gate = ws + GATE_OFF;
  float* psum = ws + PSUM_OFF;
  float* pcov = ws + PCOV_OFF;
  float* Y    = ws + Y_OFF;

  k_transpose_w<<<1, 256, 0, stream>>>(cw, wt);
  k_conv_bn_relu<<<BATCH*8, 256, 0, stream>>>(x, wt, gam, bet, mu, var, Y);
  k_covpool<<<BATCH*4, 256, 0, stream>>>(Y, pcov, psum);
  k_ns_fc<<<BATCH, 512, 0, stream>>>(pcov, psum, fcw, fcb, gate);
  k_gate_mul<<<4096, 256, 0, stream>>>(x, gate, out);
}

// Round 3
// 217.734 us; speedup vs baseline: 1.2267x; 1.0812x over previous
//
#include <hip/hip_runtime.h>
#include <math.h>

#define BATCH  128
#define CIN    256
#define HWSZ   1024
#define NATT   64
#define TRI    2080
#define PLANES 256

typedef __attribute__((ext_vector_type(8))) short short8v;
typedef __attribute__((ext_vector_type(4))) float f32x4;

// ---------------- workspace layout (floats) ----------------
static const size_t WT_OFF   = 0;                 // [CIN][NATT]        16384
static const size_t GATE_OFF = 16384;             // [BATCH][PLANES]    32768
static const size_t PSUM_OFF = 49152;             // [BATCH*4][64]      32768
static const size_t PCOV_OFF = 81920;             // [BATCH*4][64][64]  2097152
static const size_t Y_OFF    = 2179072;           // [BATCH][64][1024]  8388608

// ---------------- kernel 0: transpose conv_w ----------------
__global__ void k_transpose_w(const float* __restrict__ w, float* __restrict__ wt){
  for (int idx = threadIdx.x; idx < NATT*CIN; idx += 256){
    int o = idx >> 8;
    int c = idx & (CIN-1);
    wt[c*NATT + o] = w[o*CIN + c];
  }
}

// ---------------- kernel 1: 1x1 conv + BN + ReLU (LDS-tiled GEMM) ----------------
#define CCH 32
__global__ __launch_bounds__(256) void k_conv_bn_relu(
    const float* __restrict__ x, const float* __restrict__ wt,
    const float* __restrict__ gam, const float* __restrict__ bet,
    const float* __restrict__ mu,  const float* __restrict__ var,
    float* __restrict__ Y){
  __shared__ float xs[CCH][132];
  __shared__ float wsh[CCH][64];
  int b = blockIdx.x >> 3;
  int chunk = blockIdx.x & 7;
  int tid = threadIdx.x;
  int to = tid >> 4;
  int tp = tid & 15;
  const float* xb = x + ((size_t)b*CIN)*HWSZ + chunk*128;
  float acc[4][8];
#pragma unroll
  for (int i=0;i<4;i++)
#pragma unroll
    for (int j=0;j<8;j++) acc[i][j]=0.f;

  for (int c0=0; c0<CIN; c0+=CCH){
    __syncthreads();
#pragma unroll
    for (int k=0;k<4;k++){
      int q = tid + (k<<8);
      int r = q >> 5, col = (q & 31) << 2;
      *(float4*)&xs[r][col] = *(const float4*)(xb + (size_t)(c0+r)*HWSZ + col);
    }
#pragma unroll
    for (int k=0;k<2;k++){
      int q = tid + (k<<8);
      int r = q >> 4, col = (q & 15) << 2;
      *(float4*)&wsh[r][col] = *(const float4*)(wt + (size_t)(c0+r)*NATT + col);
    }
    __syncthreads();
#pragma unroll 8
    for (int c=0;c<CCH;c++){
      float4 wv = *(const float4*)&wsh[c][to<<2];
      float4 xa = *(const float4*)&xs[c][tp<<2];
      float4 xc = *(const float4*)&xs[c][64 + (tp<<2)];
      float xv[8] = {xa.x,xa.y,xa.z,xa.w,xc.x,xc.y,xc.z,xc.w};
      float wv4[4] = {wv.x,wv.y,wv.z,wv.w};
#pragma unroll
      for (int oo=0;oo<4;oo++)
#pragma unroll
        for (int pp=0;pp<8;pp++)
          acc[oo][pp] = fmaf(wv4[oo], xv[pp], acc[oo][pp]);
    }
  }
#pragma unroll
  for (int oo=0;oo<4;oo++){
    int o = (to<<2) + oo;
    float sc = gam[o]*rsqrtf(var[o]+1e-5f);
    float sh = bet[o] - mu[o]*sc;
    float* yp = Y + ((size_t)b*NATT + o)*HWSZ + chunk*128;
    float4 v0, v1;
    v0.x = fmaf(acc[oo][0], sc, sh); v0.y = fmaf(acc[oo][1], sc, sh);
    v0.z = fmaf(acc[oo][2], sc, sh); v0.w = fmaf(acc[oo][3], sc, sh);
    v1.x = fmaf(acc[oo][4], sc, sh); v1.y = fmaf(acc[oo][5], sc, sh);
    v1.z = fmaf(acc[oo][6], sc, sh); v1.w = fmaf(acc[oo][7], sc, sh);
    v0.x = v0.x>0.f?v0.x:0.f; v0.y = v0.y>0.f?v0.y:0.f;
    v0.z = v0.z>0.f?v0.z:0.f; v0.w = v0.w>0.f?v0.w:0.f;
    v1.x = v1.x>0.f?v1.x:0.f; v1.y = v1.y>0.f?v1.y:0.f;
    v1.z = v1.z>0.f?v1.z:0.f; v1.w = v1.w>0.f?v1.w:0.f;
    *(float4*)(yp + (tp<<2)) = v0;
    *(float4*)(yp + 64 + (tp<<2)) = v1;
  }
}

// ---------------- kernel 2: covariance pooling (partial) ----------------
__global__ __launch_bounds__(256) void k_covpool(const float* __restrict__ Y,
    float* __restrict__ pcov, float* __restrict__ psum){
  __shared__ float ys[64][132];
  __shared__ float psl[64];
  int b = blockIdx.x >> 2, quarter = blockIdx.x & 3;
  int tid = threadIdx.x;
  if (tid < 64) psl[tid] = 0.f;
  float acc[4][4];
#pragma unroll
  for (int i=0;i<4;i++)
#pragma unroll
    for (int j=0;j<4;j++) acc[i][j]=0.f;
  int i0 = (tid >> 4) << 2;
  int jb = tid & 15;
  const float* yb = Y + ((size_t)b*NATT)*HWSZ + quarter*256;

  for (int mt=0; mt<256; mt+=128){
    __syncthreads();
#pragma unroll
    for (int k=0;k<8;k++){
      int q  = tid + (k<<8);
      int r  = q >> 5;
      int cq = (q & 31) << 2;
      *(float4*)&ys[r][cq] = *(const float4*)(yb + (size_t)r*HWSZ + mt + cq);
    }
    __syncthreads();
    {
      int r = tid>>2, qt = tid&3;
      float s = 0.f;
      int base = qt<<5;
#pragma unroll
      for (int mm=0;mm<32;mm++) s += ys[r][base+mm];
      s += __shfl_down(s, 2);
      s += __shfl_down(s, 1);
      if (qt==0) psl[r] += s;
    }
    for (int m=0;m<128;m+=4){
      float am[4][4], bm[4][4];
#pragma unroll
      for (int ii=0;ii<4;ii++){
        float4 v = *(const float4*)&ys[i0+ii][m];
        am[ii][0]=v.x; am[ii][1]=v.y; am[ii][2]=v.z; am[ii][3]=v.w;
      }
#pragma unroll
      for (int jj=0;jj<4;jj++){
        float4 v = *(const float4*)&ys[jb+16*jj][m];
        bm[jj][0]=v.x; bm[jj][1]=v.y; bm[jj][2]=v.z; bm[jj][3]=v.w;
      }
#pragma unroll
      for (int ii=0;ii<4;ii++)
#pragma unroll
        for (int jj=0;jj<4;jj++){
          acc[ii][jj] = fmaf(am[ii][0], bm[jj][0], acc[ii][jj]);
          acc[ii][jj] = fmaf(am[ii][1], bm[jj][1], acc[ii][jj]);
          acc[ii][jj] = fmaf(am[ii][2], bm[jj][2], acc[ii][jj]);
          acc[ii][jj] = fmaf(am[ii][3], bm[jj][3], acc[ii][jj]);
        }
    }
  }
  float* pc = pcov + (size_t)blockIdx.x * (NATT*NATT);
#pragma unroll
  for (int ii=0;ii<4;ii++)
#pragma unroll
    for (int jj=0;jj<4;jj++)
      pc[(i0+ii)*NATT + jb + 16*jj] = acc[ii][jj];
  __syncthreads();
  if (tid < 64) psum[(size_t)blockIdx.x*64 + tid] = psl[tid];
}

// ---------------- split-precision bf16 helpers ----------------
__device__ __forceinline__ unsigned int pack_hl(float v){
  unsigned int b  = __float_as_uint(v);
  unsigned int hb = b >> 16;                       // truncated bf16 (hi)
  float hif = __uint_as_float(hb << 16);
  float lo  = v - hif;                             // |lo| <= 2^-8 |v|
  unsigned int lb = __float_as_uint(lo) >> 16;
  return hb | (lb << 16);
}

__device__ __forceinline__ void unpack8(uint4 a, uint4 b, short8v& h, short8v& l){
  unsigned int w0=a.x,w1=a.y,w2=a.z,w3=a.w,w4=b.x,w5=b.y,w6=b.z,w7=b.w;
  h[0]=(short)(w0&0xffffu); l[0]=(short)(w0>>16);
  h[1]=(short)(w1&0xffffu); l[1]=(short)(w1>>16);
  h[2]=(short)(w2&0xffffu); l[2]=(short)(w2>>16);
  h[3]=(short)(w3&0xffffu); l[3]=(short)(w3>>16);
  h[4]=(short)(w4&0xffffu); l[4]=(short)(w4>>16);
  h[5]=(short)(w5&0xffffu); l[5]=(short)(w5>>16);
  h[6]=(short)(w6&0xffffu); l[6]=(short)(w6>>16);
  h[7]=(short)(w7&0xffffu); l[7]=(short)(w7>>16);
}

// P = L @ R for 64x64 packed hi/lo matrices (R symmetric: B-frags read row-wise).
// wave: rp = row panel (16 rows), ch = col half (2 x 16x16 tiles). 3 MFMA per tile/kstep.
__device__ __forceinline__ void wave_mm(const unsigned int (*PL)[68],
                                        const unsigned int (*PR)[68],
                                        int lane, int rp, int ch, f32x4* acc){
  f32x4 z = {0.f,0.f,0.f,0.f};
  acc[0] = z; acc[1] = z;
  int i15 = lane & 15, q = lane >> 4;
  int row = rp*16 + i15;
#pragma unroll
  for (int s=0; s<2; s++){
    int kbase = s*32 + (q<<3);
    uint4 a0 = *(const uint4*)&PL[row][kbase];
    uint4 a1 = *(const uint4*)&PL[row][kbase+4];
    short8v ah, al; unpack8(a0,a1,ah,al);
#pragma unroll
    for (int ct=0; ct<2; ct++){
      const unsigned int* bp = &PR[ch*32 + ct*16 + i15][kbase];
      uint4 b0 = *(const uint4*)bp;
      uint4 b1 = *(const uint4*)(bp+4);
      short8v bh, bl; unpack8(b0,b1,bh,bl);
      acc[ct] = __builtin_amdgcn_mfma_f32_16x16x32_bf16(ah, bh, acc[ct], 0,0,0);
      acc[ct] = __builtin_amdgcn_mfma_f32_16x16x32_bf16(ah, bl, acc[ct], 0,0,0);
      acc[ct] = __builtin_amdgcn_mfma_f32_16x16x32_bf16(al, bh, acc[ct], 0,0,0);
    }
  }
}

// MODE 0: pack(v)   MODE 1: pack(0.5*(3I - v))   MODE 2: pack(3I - v)
template<int MODE>
__device__ __forceinline__ void store_packed(unsigned int (*PD)[68], const f32x4* acc,
                                             int lane, int rp, int ch){
  int i15 = lane & 15, q = lane >> 4;
#pragma unroll
  for (int ct=0; ct<2; ct++){
    int col = ch*32 + ct*16 + i15;
#pragma unroll
    for (int r=0; r<4; r++){
      int row = rp*16 + q*4 + r;
      float v = acc[ct][r];
      if (MODE==1) v = 0.5f*((row==col?3.f:0.f) - v);
      if (MODE==2) v = (row==col?3.f:0.f) - v;
      PD[row][col] = pack_hl(v);
    }
  }
}

// ---------------- kernel 3: Newton-Schulz (MFMA) + triuvec + FC + sigmoid ----------------
// grid: BATCH blocks, 512 threads (8 waves: 4 row-panels x 2 col-halves).
__global__ __launch_bounds__(512) void k_ns_fc(const float* __restrict__ pcov,
    const float* __restrict__ psum, const float* __restrict__ fcw,
    const float* __restrict__ fcb, float* __restrict__ gate){
  __shared__ float Af[64][68];
  __shared__ unsigned int PA[64][68];
  __shared__ unsigned int PT[64][68];
  __shared__ unsigned int PY[64][68];
  __shared__ unsigned int PZ[64][68];
  __shared__ __align__(16) float vec[TRI];
  __shared__ float meanl[64];
  __shared__ float snorm;
  int b = blockIdx.x, tid = threadIdx.x;
  int lane = tid & 63, wv = tid >> 6, rp = wv & 3, ch = wv >> 2;
  const float* pc0 = pcov + ((size_t)b*4) * (NATT*NATT);
  if (tid < 64){
    const float* ps = psum + (size_t)b*256;
    meanl[tid] = (ps[tid] + ps[64+tid] + ps[128+tid] + ps[192+tid]) * (1.f/1024.f);
  }
  __syncthreads();
  for (int e=tid; e<4096; e+=512){
    int i = e>>6, j = e&63;
    Af[i][j] = (pc0[e] + pc0[4096+e] + pc0[8192+e] + pc0[12288+e]) * (1.f/1024.f)
              - meanl[i]*meanl[j];
  }
  __syncthreads();
  if (tid < 64){
    float s = Af[tid][tid];
#pragma unroll
    for (int off=32; off; off>>=1) s += __shfl_down(s, off);
    if (tid==0) snorm = s;
  }
  __syncthreads();
  float normA = snorm;
  float inv = 1.f/normA;
  for (int e=tid; e<4096; e+=512){
    int i = e>>6, j = e&63;
    float an = Af[i][j]*inv;
    float t  = 0.5f*((i==j?3.f:0.f) - an);
    unsigned int pt = pack_hl(t);
    PA[i][j] = pack_hl(an);
    PT[i][j] = pt;
    PZ[i][j] = pt;
  }
  __syncthreads();

  f32x4 accY[2], accZ[2];
  // Y0 = An @ T0
  wave_mm(PA, PT, lane, rp, ch, accY);
  store_packed<0>(PY, accY, lane, rp, ch);
  __syncthreads();

  for (int it=0; it<3; ++it){
    // T = 0.5*(3I - Z@Y)
    wave_mm(PZ, PY, lane, rp, ch, accY);
    store_packed<1>(PT, accY, lane, rp, ch);
    __syncthreads();
    // Yn = Y@T ; Zn = T@Z  (both into regs before overwriting)
    wave_mm(PY, PT, lane, rp, ch, accY);
    wave_mm(PT, PZ, lane, rp, ch, accZ);
    __syncthreads();
    store_packed<0>(PY, accY, lane, rp, ch);
    store_packed<0>(PZ, accZ, lane, rp, ch);
    __syncthreads();
  }
  // final: F = 0.5 * Y @ (3I - Z@Y) * sqrt(normA)
  wave_mm(PZ, PY, lane, rp, ch, accY);
  store_packed<2>(PT, accY, lane, rp, ch);
  __syncthreads();
  wave_mm(PY, PT, lane, rp, ch, accY);
  float scl = 0.5f * sqrtf(normA);
  {
    int i15 = lane & 15, q = lane >> 4;
#pragma unroll
    for (int ct=0; ct<2; ct++){
      int col = ch*32 + ct*16 + i15;
#pragma unroll
      for (int r=0; r<4; r++){
        int row = rp*16 + q*4 + r;
        Af[row][col] = accY[ct][r]*scl;
      }
    }
  }
  __syncthreads();
  // triuvec
  for (int e=tid; e<4096; e+=512){
    int i = e>>6, j = e&63;
    if (j >= i){
      int t0 = (i*(129 - i)) >> 1;
      vec[t0 + j - i] = Af[i][j];
    }
  }
  __syncthreads();
  // FC + sigmoid: 2 threads per plane
  {
    int p  = tid >> 1;
    int hf = tid & 1;
    const float* wr = fcw + (size_t)p*TRI + hf*1040;
    const float* vr = vec + hf*1040;
    float acc = 0.f;
    for (int t=0; t<1040; t+=4){
      float4 wvv = *(const float4*)(wr + t);
      float4 vv  = *(const float4*)(vr + t);
      acc = fmaf(wvv.x, vv.x, acc);
      acc = fmaf(wvv.y, vv.y, acc);
      acc = fmaf(wvv.z, vv.z, acc);
      acc = fmaf(wvv.w, vv.w, acc);
    }
    acc += __shfl_xor(acc, 1);
    if (hf==0)
      gate[(size_t)b*PLANES + p] = 1.f/(1.f + expf(-(acc + fcb[p])));
  }
}

// ---------------- kernel 4: out = x * gate[b,c] (grid-stride) ----------------
__global__ __launch_bounds__(256) void k_gate_mul(const float* __restrict__ x,
    const float* __restrict__ gate, float* __restrict__ out){
  size_t base = (size_t)blockIdx.x*256 + threadIdx.x;
#pragma unroll
  for (int k=0;k<8;k++){
    size_t i4 = base + (size_t)k*1048576;
    size_t e  = i4 << 2;
    int bc = (int)(e >> 10);
    float g = gate[bc];
    float4 v = *(const float4*)(x + e);
    v.x *= g; v.y *= g; v.z *= g; v.w *= g;
    *(float4*)(out + e) = v;
  }
}

extern "C" void kernel_launch(void* const* d_in, const int* in_sizes, int n_in,
                              void* d_out, int out_size, void* d_ws, size_t ws_size,
                              hipStream_t stream) {
  const float* x    = (const float*)d_in[0];
  const float* cw   = (const float*)d_in[1];
  const float* gam  = (const float*)d_in[2];
  const float* bet  = (const float*)d_in[3];
  const float* mu   = (const float*)d_in[4];
  const float* var  = (const float*)d_in[5];
  const float* fcw  = (const float*)d_in[6];
  const float* fcb  = (const float*)d_in[7];
  float* out = (float*)d_out;
  float* ws  = (float*)d_ws;

  float* wt   = ws + WT_OFF;
  float* gate = ws + GATE_OFF;
  float* psum = ws + PSUM_OFF;
  float* pcov = ws + PCOV_OFF;
  float* Y    = ws + Y_OFF;

  k_transpose_w<<<1, 256, 0, stream>>>(cw, wt);
  k_conv_bn_relu<<<BATCH*8, 256, 0, stream>>>(x, wt, gam, bet, mu, var, Y);
  k_covpool<<<BATCH*4, 256, 0, stream>>>(Y, pcov, psum);
  k_ns_fc<<<BATCH, 512, 0, stream>>>(pcov, psum, fcw, fcb, gate);
  k_gate_mul<<<4096, 256, 0, stream>>>(x, gate, out);
}

// Round 4
// 171.163 us; speedup vs baseline: 1.5604x; 1.2721x over previous
//
#include <hip/hip_runtime.h>
#include <math.h>

#define BATCH  128
#define CIN    256
#define HWSZ   1024
#define NATT   64
#define TRI    2080
#define PLANES 256

typedef __attribute__((ext_vector_type(8))) short short8v;
typedef __attribute__((ext_vector_type(4))) float f32x4;

// ---------------- workspace layout (float slots) ----------------
static const size_t WPACK_OFF = 0;        // uint [64][256]      16384
static const size_t GATE_OFF  = 16384;    // [128][256]          32768
static const size_t PSUM_OFF  = 49152;    // [512][64]           32768
static const size_t PGRAM_OFF = 81920;    // [512][64][64]       2097152
static const size_t VEC_OFF   = 2179072;  // [128][2080]         266240

// ---------------- split-precision helpers ----------------
__device__ __forceinline__ unsigned int pack_hl(float v){
  unsigned int b  = __float_as_uint(v);
  unsigned int hb = b >> 16;                       // truncated bf16 (hi)
  float hif = __uint_as_float(hb << 16);
  float lo  = v - hif;
  unsigned int lb = __float_as_uint(lo) >> 16;
  return hb | (lb << 16);
}

__device__ __forceinline__ void unpack8a(const unsigned int* w, short8v& h, short8v& l){
#pragma unroll
  for (int i=0;i<8;i++){ h[i]=(short)(w[i]&0xffffu); l[i]=(short)(w[i]>>16); }
}

__device__ __forceinline__ void unpack8(uint4 a, uint4 b, short8v& h, short8v& l){
  unsigned int w[8] = {a.x,a.y,a.z,a.w,b.x,b.y,b.z,b.w};
  unpack8a(w, h, l);
}

// ---------------- kernel 0: pack conv_w to bf16 hi/lo ----------------
__global__ void k_pack_w(const float* __restrict__ w, unsigned int* __restrict__ wp){
  for (int idx = threadIdx.x; idx < NATT*CIN; idx += 256)
    wp[idx] = pack_hl(w[idx]);
}

// ---------------- kernel 1: fused conv+BN+ReLU+gram (MFMA split-bf16) --------
// grid: 128 b x 4 pixel-chunks (256 px) = 512 blocks, 512 threads (8 waves).
// conv: out[64 o][256 p] via A=w[o][c], B=x[c][p]; waves = 4 o-panels x 2 p-halves.
// then Y tile packed in LDS; gram[64][64] partial + row sums written to ws.
__global__ __launch_bounds__(512) void k_conv_gram(
    const float* __restrict__ x, const unsigned int* __restrict__ wpack,
    const float* __restrict__ gam, const float* __restrict__ bet,
    const float* __restrict__ mu,  const float* __restrict__ var,
    float* __restrict__ pgram, float* __restrict__ psum){
  __shared__ unsigned int xs[32][257];   // stride 257: bank = c + p  (2-way max)
  __shared__ unsigned int yt[64][257];
  __shared__ float scl[64], shf[64];
  int bid = blockIdx.x;
  int b = bid >> 2, chunk = bid & 3;
  int tid = threadIdx.x;
  int l = tid & 63, w = tid >> 6;
  int row16 = l & 15, q = l >> 4;
  int o0 = (w & 3) * 16, pb = (w >> 2) * 128;
  if (tid < 64){
    float sc = gam[tid]*rsqrtf(var[tid]+1e-5f);
    scl[tid] = sc; shf[tid] = bet[tid] - mu[tid]*sc;
  }
  const float* xb = x + ((size_t)b*CIN)*HWSZ + chunk*256;
  f32x4 acc[8];
#pragma unroll
  for (int t=0;t<8;t++) acc[t] = (f32x4){0.f,0.f,0.f,0.f};
  int cstage = tid & 7, pstage = (tid>>3) << 2;

  for (int cc=0; cc<8; ++cc){
    int c0 = cc*32;
    __syncthreads();
    // stage 32c x 256p packed (coalesced 128B segments per c-row)
#pragma unroll
    for (int k=0;k<4;k++){
      int cL = cstage + 8*k;
      float4 v = *(const float4*)(xb + (size_t)(c0+cL)*HWSZ + pstage);
      xs[cL][pstage]   = pack_hl(v.x);
      xs[cL][pstage+1] = pack_hl(v.y);
      xs[cL][pstage+2] = pack_hl(v.z);
      xs[cL][pstage+3] = pack_hl(v.w);
    }
    __syncthreads();
    // A-frag from global (L2-resident, reused by all 512 blocks)
    const unsigned int* wp = wpack + (o0+row16)*256 + c0 + q*8;
    uint4 a0 = *(const uint4*)wp;
    uint4 a1 = *(const uint4*)(wp+4);
    short8v ah, al; unpack8(a0,a1,ah,al);
#pragma unroll
    for (int t=0;t<8;t++){
      int p0 = pb + t*16;
      unsigned int bw[8];
#pragma unroll
      for (int e=0;e<8;e++) bw[e] = xs[q*8+e][p0+row16];
      short8v bh, bl; unpack8a(bw, bh, bl);
      acc[t] = __builtin_amdgcn_mfma_f32_16x16x32_bf16(ah, bh, acc[t],0,0,0);
      acc[t] = __builtin_amdgcn_mfma_f32_16x16x32_bf16(ah, bl, acc[t],0,0,0);
      acc[t] = __builtin_amdgcn_mfma_f32_16x16x32_bf16(al, bh, acc[t],0,0,0);
    }
  }
  __syncthreads();
  // epilogue: BN + ReLU + pack -> yt[o][p]
#pragma unroll
  for (int t=0;t<8;t++){
    int p = pb + t*16 + row16;
#pragma unroll
    for (int r=0;r<4;r++){
      int o = o0 + q*4 + r;
      float v = fmaf(acc[t][r], scl[o], shf[o]);
      v = v>0.f ? v : 0.f;
      yt[o][p] = pack_hl(v);
    }
  }
  __syncthreads();
  // row sums (for the mean): 8 threads per row
  {
    int row = tid>>3, seg = tid&7;
    float s = 0.f;
#pragma unroll
    for (int m=0;m<32;m++){
      unsigned int u = yt[row][seg*32+m];
      s += __uint_as_float(u<<16) + __uint_as_float(u & 0xffff0000u);
    }
    s += __shfl_down(s, 4, 8);
    s += __shfl_down(s, 2, 8);
    s += __shfl_down(s, 1, 8);
    if (seg==0) psum[(size_t)bid*64 + row] = s;
  }
  // gram = Y @ Y^T over this chunk's 256 px: wave w -> tiles 2w, 2w+1
  {
    f32x4 g0 = (f32x4){0.f,0.f,0.f,0.f}, g1 = g0;
    int ti = w >> 1;
    int tj0 = (w & 1) * 2;
#pragma unroll
    for (int ks=0; ks<8; ks++){
      int k0 = ks*32 + q*8;
      unsigned int aw[8], b0w[8], b1w[8];
#pragma unroll
      for (int e=0;e<8;e++){
        aw[e]  = yt[ti*16  + row16][k0+e];
        b0w[e] = yt[tj0*16 + row16][k0+e];
        b1w[e] = yt[(tj0+1)*16 + row16][k0+e];
      }
      short8v ah2, al2, bh0, bl0, bh1, bl1;
      unpack8a(aw,  ah2, al2);
      unpack8a(b0w, bh0, bl0);
      unpack8a(b1w, bh1, bl1);
      g0 = __builtin_amdgcn_mfma_f32_16x16x32_bf16(ah2, bh0, g0,0,0,0);
      g0 = __builtin_amdgcn_mfma_f32_16x16x32_bf16(ah2, bl0, g0,0,0,0);
      g0 = __builtin_amdgcn_mfma_f32_16x16x32_bf16(al2, bh0, g0,0,0,0);
      g1 = __builtin_amdgcn_mfma_f32_16x16x32_bf16(ah2, bh1, g1,0,0,0);
      g1 = __builtin_amdgcn_mfma_f32_16x16x32_bf16(ah2, bl1, g1,0,0,0);
      g1 = __builtin_amdgcn_mfma_f32_16x16x32_bf16(al2, bh1, g1,0,0,0);
    }
    float* pg = pgram + (size_t)bid*4096;
#pragma unroll
    for (int r=0;r<4;r++){
      int i = ti*16 + q*4 + r;
      pg[i*64 + tj0*16     + row16] = g0[r];
      pg[i*64 + (tj0+1)*16 + row16] = g1[r];
    }
  }
}

// P = L @ R for 64x64 packed hi/lo (R symmetric: B-frags read row-wise).
__device__ __forceinline__ void wave_mm(const unsigned int (*PL)[68],
                                        const unsigned int (*PR)[68],
                                        int lane, int rp, int ch, f32x4* acc){
  f32x4 z = {0.f,0.f,0.f,0.f};
  acc[0] = z; acc[1] = z;
  int i15 = lane & 15, q = lane >> 4;
  int row = rp*16 + i15;
#pragma unroll
  for (int s=0; s<2; s++){
    int kbase = s*32 + (q<<3);
    uint4 a0 = *(const uint4*)&PL[row][kbase];
    uint4 a1 = *(const uint4*)&PL[row][kbase+4];
    short8v ah, al; unpack8(a0,a1,ah,al);
#pragma unroll
    for (int ct=0; ct<2; ct++){
      const unsigned int* bp = &PR[ch*32 + ct*16 + i15][kbase];
      uint4 b0 = *(const uint4*)bp;
      uint4 b1 = *(const uint4*)(bp+4);
      short8v bh, bl; unpack8(b0,b1,bh,bl);
      acc[ct] = __builtin_amdgcn_mfma_f32_16x16x32_bf16(ah, bh, acc[ct], 0,0,0);
      acc[ct] = __builtin_amdgcn_mfma_f32_16x16x32_bf16(ah, bl, acc[ct], 0,0,0);
      acc[ct] = __builtin_amdgcn_mfma_f32_16x16x32_bf16(al, bh, acc[ct], 0,0,0);
    }
  }
}

template<int MODE>  // 0: pack(v)  1: pack(0.5*(3I-v))  2: pack(3I-v)
__device__ __forceinline__ void store_packed(unsigned int (*PD)[68], const f32x4* acc,
                                             int lane, int rp, int ch){
  int i15 = lane & 15, q = lane >> 4;
#pragma unroll
  for (int ct=0; ct<2; ct++){
    int col = ch*32 + ct*16 + i15;
#pragma unroll
    for (int r=0; r<4; r++){
      int row = rp*16 + q*4 + r;
      float v = acc[ct][r];
      if (MODE==1) v = 0.5f*((row==col?3.f:0.f) - v);
      if (MODE==2) v = (row==col?3.f:0.f) - v;
      PD[row][col] = pack_hl(v);
    }
  }
}

// ---------------- kernel 2: Newton-Schulz + triuvec -> vec ----------------
__global__ __launch_bounds__(512) void k_ns(const float* __restrict__ pgram,
    const float* __restrict__ psum, float* __restrict__ vecg){
  __shared__ float Af[64][68];
  __shared__ unsigned int PA[64][68];
  __shared__ unsigned int PT[64][68];
  __shared__ unsigned int PY[64][68];
  __shared__ unsigned int PZ[64][68];
  __shared__ float meanl[64];
  __shared__ float snorm;
  int b = blockIdx.x, tid = threadIdx.x;
  int lane = tid & 63, wv = tid >> 6, rp = wv & 3, ch = wv >> 2;
  const float* pc0 = pgram + ((size_t)b*4) * (NATT*NATT);
  if (tid < 64){
    const float* ps = psum + (size_t)b*256;
    meanl[tid] = (ps[tid] + ps[64+tid] + ps[128+tid] + ps[192+tid]) * (1.f/1024.f);
  }
  __syncthreads();
  for (int e=tid; e<4096; e+=512){
    int i = e>>6, j = e&63;
    Af[i][j] = (pc0[e] + pc0[4096+e] + pc0[8192+e] + pc0[12288+e]) * (1.f/1024.f)
              - meanl[i]*meanl[j];
  }
  __syncthreads();
  if (tid < 64){
    float s = Af[tid][tid];
#pragma unroll
    for (int off=32; off; off>>=1) s += __shfl_down(s, off);
    if (tid==0) snorm = s;
  }
  __syncthreads();
  float normA = snorm;
  float inv = 1.f/normA;
  for (int e=tid; e<4096; e+=512){
    int i = e>>6, j = e&63;
    float an = Af[i][j]*inv;
    float t  = 0.5f*((i==j?3.f:0.f) - an);
    unsigned int pt = pack_hl(t);
    PA[i][j] = pack_hl(an);
    PT[i][j] = pt;
    PZ[i][j] = pt;
  }
  __syncthreads();

  f32x4 accY[2], accZ[2];
  wave_mm(PA, PT, lane, rp, ch, accY);
  store_packed<0>(PY, accY, lane, rp, ch);
  __syncthreads();

  for (int it=0; it<3; ++it){
    wave_mm(PZ, PY, lane, rp, ch, accY);
    store_packed<1>(PT, accY, lane, rp, ch);
    __syncthreads();
    wave_mm(PY, PT, lane, rp, ch, accY);
    wave_mm(PT, PZ, lane, rp, ch, accZ);
    __syncthreads();
    store_packed<0>(PY, accY, lane, rp, ch);
    store_packed<0>(PZ, accZ, lane, rp, ch);
    __syncthreads();
  }
  wave_mm(PZ, PY, lane, rp, ch, accY);
  store_packed<2>(PT, accY, lane, rp, ch);
  __syncthreads();
  wave_mm(PY, PT, lane, rp, ch, accY);
  float scl = 0.5f * sqrtf(normA);
  {
    int i15 = lane & 15, q = lane >> 4;
#pragma unroll
    for (int ct=0; ct<2; ct++){
      int col = ch*32 + ct*16 + i15;
#pragma unroll
      for (int r=0; r<4; r++){
        int row = rp*16 + q*4 + r;
        Af[row][col] = accY[ct][r]*scl;
      }
    }
  }
  __syncthreads();
  // triuvec -> global vec
  float* vp = vecg + (size_t)b*TRI;
  for (int e=tid; e<4096; e+=512){
    int i = e>>6, j = e&63;
    if (j >= i){
      int t0 = (i*(129 - i)) >> 1;
      vp[t0 + j - i] = Af[i][j];
    }
  }
}

// ---------------- kernel 3: FC + sigmoid ----------------
// grid: 128 blocks = 8 batch-groups x 16 plane-groups; 512 threads.
// fcw tile [16 planes][2080] resident in LDS; 16 batches per block.
__global__ __launch_bounds__(512) void k_fc(const float* __restrict__ vecg,
    const float* __restrict__ fcw, const float* __restrict__ fcb,
    float* __restrict__ gate){
  __shared__ float fwL[16][2080];
  __shared__ __align__(16) float vecL[2080];
  int bg = blockIdx.x >> 4, pg = blockIdx.x & 15;
  int tid = threadIdx.x;
  for (int i=tid; i<8320; i+=512){
    int row = i/520, c4 = i - row*520;
    *(float4*)&fwL[row][c4<<2] = *(const float4*)(fcw + (size_t)(pg*16+row)*TRI + (c4<<2));
  }
  int p = tid >> 5, s = tid & 31;
  int base = s*65;
  float bias = fcb[pg*16 + p];
  for (int bi=0; bi<16; ++bi){
    int b = bg*16 + bi;
    __syncthreads();
    for (int i=tid; i<520; i+=512)
      *(float4*)&vecL[i<<2] = *(const float4*)(vecg + (size_t)b*TRI + (i<<2));
    __syncthreads();
    float acc = 0.f;
#pragma unroll 13
    for (int m=0; m<65; ++m)
      acc = fmaf(fwL[p][base+m], vecL[base+m], acc);
    acc += __shfl_down(acc, 16, 32);
    acc += __shfl_down(acc, 8, 32);
    acc += __shfl_down(acc, 4, 32);
    acc += __shfl_down(acc, 2, 32);
    acc += __shfl_down(acc, 1, 32);
    if (s==0)
      gate[(size_t)b*PLANES + pg*16 + p] = 1.f/(1.f + expf(-(acc + bias)));
  }
}

// ---------------- kernel 4: out = x * gate[b,c] ----------------
__global__ __launch_bounds__(256) void k_gate_mul(const float* __restrict__ x,
    const float* __restrict__ gate, float* __restrict__ out){
  size_t base = (size_t)blockIdx.x*256 + threadIdx.x;
#pragma unroll
  for (int k=0;k<8;k++){
    size_t i4 = base + (size_t)k*1048576;
    size_t e  = i4 << 2;
    int bc = (int)(e >> 10);
    float g = gate[bc];
    float4 v = *(const float4*)(x + e);
    v.x *= g; v.y *= g; v.z *= g; v.w *= g;
    *(float4*)(out + e) = v;
  }
}

extern "C" void kernel_launch(void* const* d_in, const int* in_sizes, int n_in,
                              void* d_out, int out_size, void* d_ws, size_t ws_size,
                              hipStream_t stream) {
  const float* x    = (const float*)d_in[0];
  const float* cw   = (const float*)d_in[1];
  const float* gam  = (const float*)d_in[2];
  const float* bet  = (const float*)d_in[3];
  const float* mu   = (const float*)d_in[4];
  const float* var  = (const float*)d_in[5];
  const float* fcw  = (const float*)d_in[6];
  const float* fcb  = (const float*)d_in[7];
  float* out = (float*)d_out;
  float* ws  = (float*)d_ws;

  unsigned int* wpack = (unsigned int*)(ws + WPACK_OFF);
  float* gate  = ws + GATE_OFF;
  float* psum  = ws + PSUM_OFF;
  float* pgram = ws + PGRAM_OFF;
  float* vecg  = ws + VEC_OFF;

  k_pack_w<<<1, 256, 0, stream>>>(cw, wpack);
  k_conv_gram<<<BATCH*4, 512, 0, stream>>>(x, wpack, gam, bet, mu, var, pgram, psum);
  k_ns<<<BATCH, 512, 0, stream>>>(pgram, psum, vecg);
  k_fc<<<128, 512, 0, stream>>>(vecg, fcw, fcb, gate);
  k_gate_mul<<<4096, 256, 0, stream>>>(x, gate, out);
}

// Round 5
// 157.753 us; speedup vs baseline: 1.6931x; 1.0850x over previous
//
#include <hip/hip_runtime.h>
#include <math.h>

#define BATCH  128
#define CIN    256
#define HWSZ   1024
#define NATT   64
#define TRI    2080
#define PLANES 256

typedef __attribute__((ext_vector_type(8))) short short8v;
typedef __attribute__((ext_vector_type(4))) float f32x4;

// ---------------- workspace layout (float slots) ----------------
static const size_t WPACK_OFF = 0;         // uint [64][256]       16384
static const size_t GATE_OFF  = 16384;     // [128][256]           32768
static const size_t PSUM_OFF  = 49152;     // [1024][64]           65536
static const size_t PGRAM_OFF = 114688;    // [1024][64][64]       4194304
static const size_t VEC_OFF   = 4308992;   // [128][2080]          266240

// ---------------- split-precision helpers ----------------
__device__ __forceinline__ unsigned int pack_hl(float v){
  unsigned int b  = __float_as_uint(v);
  unsigned int hb = b >> 16;                       // truncated bf16 (hi)
  float hif = __uint_as_float(hb << 16);
  float lo  = v - hif;
  unsigned int lb = __float_as_uint(lo) >> 16;
  return hb | (lb << 16);
}

// 8 packed uints -> hi/lo bf16x8 via v_perm (2 ops per dword pair)
__device__ __forceinline__ void unpack8p(const unsigned int* w, short8v& h, short8v& l){
  union { unsigned int u[4]; short8v s; } H, L;
#pragma unroll
  for (int i=0;i<4;i++){
    H.u[i] = __builtin_amdgcn_perm(w[2*i+1], w[2*i], 0x05040100u);
    L.u[i] = __builtin_amdgcn_perm(w[2*i+1], w[2*i], 0x07060302u);
  }
  h = H.s; l = L.s;
}
__device__ __forceinline__ void unpack8v(uint4 a, uint4 b, short8v& h, short8v& l){
  unsigned int w[8] = {a.x,a.y,a.z,a.w,b.x,b.y,b.z,b.w};
  unpack8p(w, h, l);
}

// ---------------- kernel 0: pack conv_w to bf16 hi/lo ----------------
__global__ void k_pack_w(const float* __restrict__ w, unsigned int* __restrict__ wp){
  for (int idx = threadIdx.x; idx < NATT*CIN; idx += 256)
    wp[idx] = pack_hl(w[idx]);
}

// ---------------- kernel 1: fused conv+BN+ReLU+gram ----------------
// grid: 128 b x 8 chunks (128 px) = 1024 blocks, 512 threads (8 waves).
// conv tile 64o x 128p: wave = (o-panel w&3, p-half w>>2), 4 16x16 tiles each.
// xs[p][c] transposed packed tile (stride 36), yt[o][p] packed (stride 132).
__global__ __launch_bounds__(512, 4) void k_conv_gram(
    const float* __restrict__ x, const unsigned int* __restrict__ wpack,
    const float* __restrict__ gam, const float* __restrict__ bet,
    const float* __restrict__ mu,  const float* __restrict__ var,
    float* __restrict__ pgram, float* __restrict__ psum){
  __shared__ unsigned int xs[128][36];
  __shared__ unsigned int yt[64][132];
  __shared__ float scl[64], shf[64];
  __shared__ float psl[2][64];
  int bid = blockIdx.x;
  int b = bid >> 3, chunk = bid & 7;
  int tid = threadIdx.x;
  int l = tid & 63, w = tid >> 6;
  int i16 = l & 15, q = l >> 4;
  int o0 = (w & 3) * 16, phalf = (w >> 2) * 64;
  if (tid < 64){
    float sc = gam[tid]*rsqrtf(var[tid]+1e-5f);
    scl[tid] = sc; shf[tid] = bet[tid] - mu[tid]*sc;
  }
  const float* xb = x + ((size_t)b*CIN)*HWSZ + chunk*128;
  int cS = tid >> 4;          // staging channel 0..31
  int pS = tid & 15;          // staging pixel base
  f32x4 acc[4];
#pragma unroll
  for (int t=0;t<4;t++) acc[t] = (f32x4){0.f,0.f,0.f,0.f};

  for (int cc=0; cc<8; ++cc){
    int c0 = cc*32;
    __syncthreads();
    // stage transposed: xs[p][c] for c0..c0+31, p 0..127 (banks 2-way)
#pragma unroll
    for (int j=0;j<8;j++){
      int p = pS + 16*j;
      xs[p][cS] = pack_hl(xb[(size_t)(c0+cS)*HWSZ + p]);
    }
    __syncthreads();
    // A-frag (weights) from global, L2-hot
    const unsigned int* wp = wpack + (o0+i16)*256 + c0 + q*8;
    uint4 a0 = *(const uint4*)wp;
    uint4 a1 = *(const uint4*)(wp+4);
    short8v ah, al; unpack8v(a0,a1,ah,al);
#pragma unroll
    for (int t=0;t<4;t++){
      int p = phalf + t*16 + i16;
      uint4 b0 = *(const uint4*)&xs[p][q*8];
      uint4 b1 = *(const uint4*)&xs[p][q*8+4];
      short8v bh, bl; unpack8v(b0,b1,bh,bl);
      acc[t] = __builtin_amdgcn_mfma_f32_16x16x32_bf16(ah, bh, acc[t],0,0,0);
      acc[t] = __builtin_amdgcn_mfma_f32_16x16x32_bf16(ah, bl, acc[t],0,0,0);
      acc[t] = __builtin_amdgcn_mfma_f32_16x16x32_bf16(al, bh, acc[t],0,0,0);
    }
  }
  __syncthreads();
  // epilogue: BN + ReLU in regs, pack -> yt; row sums via 16-lane shuffles
  float rs[4] = {0.f,0.f,0.f,0.f};
#pragma unroll
  for (int t=0;t<4;t++){
    int p = phalf + t*16 + i16;
#pragma unroll
    for (int r=0;r<4;r++){
      int o = o0 + q*4 + r;
      float v = fmaf(acc[t][r], scl[o], shf[o]);
      v = v>0.f ? v : 0.f;
      yt[o][p] = pack_hl(v);
      rs[r] += v;
    }
  }
#pragma unroll
  for (int r=0;r<4;r++){
#pragma unroll
    for (int m=1;m<16;m<<=1) rs[r] += __shfl_xor(rs[r], m, 16);
  }
  if (i16 == 0){
#pragma unroll
    for (int r=0;r<4;r++) psl[w>>2][o0 + q*4 + r] = rs[r];
  }
  __syncthreads();
  if (tid < 64) psum[(size_t)bid*64 + tid] = psl[0][tid] + psl[1][tid];
  // gram = Y Y^T over 128 px: wave -> tiles (ti, tj0), (ti, tj0+1)
  {
    f32x4 g0 = (f32x4){0.f,0.f,0.f,0.f}, g1 = g0;
    int ti = w >> 1, tj0 = (w & 1) * 2;
#pragma unroll
    for (int ks=0; ks<4; ks++){
      int k0 = ks*32 + q*8;
      uint4 a0 = *(const uint4*)&yt[ti*16 + i16][k0];
      uint4 a1 = *(const uint4*)&yt[ti*16 + i16][k0+4];
      short8v ah2, al2; unpack8v(a0,a1,ah2,al2);
      uint4 c0v = *(const uint4*)&yt[tj0*16 + i16][k0];
      uint4 c1v = *(const uint4*)&yt[tj0*16 + i16][k0+4];
      short8v bh0, bl0; unpack8v(c0v,c1v,bh0,bl0);
      uint4 d0v = *(const uint4*)&yt[(tj0+1)*16 + i16][k0];
      uint4 d1v = *(const uint4*)&yt[(tj0+1)*16 + i16][k0+4];
      short8v bh1, bl1; unpack8v(d0v,d1v,bh1,bl1);
      g0 = __builtin_amdgcn_mfma_f32_16x16x32_bf16(ah2, bh0, g0,0,0,0);
      g0 = __builtin_amdgcn_mfma_f32_16x16x32_bf16(ah2, bl0, g0,0,0,0);
      g0 = __builtin_amdgcn_mfma_f32_16x16x32_bf16(al2, bh0, g0,0,0,0);
      g1 = __builtin_amdgcn_mfma_f32_16x16x32_bf16(ah2, bh1, g1,0,0,0);
      g1 = __builtin_amdgcn_mfma_f32_16x16x32_bf16(ah2, bl1, g1,0,0,0);
      g1 = __builtin_amdgcn_mfma_f32_16x16x32_bf16(al2, bh1, g1,0,0,0);
    }
    float* pg = pgram + (size_t)bid*4096;
#pragma unroll
    for (int r=0;r<4;r++){
      int i = ti*16 + q*4 + r;
      pg[i*64 + tj0*16     + i16] = g0[r];
      pg[i*64 + (tj0+1)*16 + i16] = g1[r];
    }
  }
}

// P = L @ R for 64x64 packed hi/lo (R symmetric: B-frags read row-wise).
__device__ __forceinline__ void wave_mm(const unsigned int (*PL)[68],
                                        const unsigned int (*PR)[68],
                                        int lane, int rp, int ch, f32x4* acc){
  f32x4 z = {0.f,0.f,0.f,0.f};
  acc[0] = z; acc[1] = z;
  int i15 = lane & 15, q = lane >> 4;
  int row = rp*16 + i15;
#pragma unroll
  for (int s=0; s<2; s++){
    int kbase = s*32 + (q<<3);
    uint4 a0 = *(const uint4*)&PL[row][kbase];
    uint4 a1 = *(const uint4*)&PL[row][kbase+4];
    short8v ah, al; unpack8v(a0,a1,ah,al);
#pragma unroll
    for (int ct=0; ct<2; ct++){
      const unsigned int* bp = &PR[ch*32 + ct*16 + i15][kbase];
      uint4 b0 = *(const uint4*)bp;
      uint4 b1 = *(const uint4*)(bp+4);
      short8v bh, bl; unpack8v(b0,b1,bh,bl);
      acc[ct] = __builtin_amdgcn_mfma_f32_16x16x32_bf16(ah, bh, acc[ct], 0,0,0);
      acc[ct] = __builtin_amdgcn_mfma_f32_16x16x32_bf16(ah, bl, acc[ct], 0,0,0);
      acc[ct] = __builtin_amdgcn_mfma_f32_16x16x32_bf16(al, bh, acc[ct], 0,0,0);
    }
  }
}

template<int MODE>  // 0: pack(v)  1: pack(0.5*(3I-v))  2: pack(3I-v)
__device__ __forceinline__ void store_packed(unsigned int (*PD)[68], const f32x4* acc,
                                             int lane, int rp, int ch){
  int i15 = lane & 15, q = lane >> 4;
#pragma unroll
  for (int ct=0; ct<2; ct++){
    int col = ch*32 + ct*16 + i15;
#pragma unroll
    for (int r=0; r<4; r++){
      int row = rp*16 + q*4 + r;
      float v = acc[ct][r];
      if (MODE==1) v = 0.5f*((row==col?3.f:0.f) - v);
      if (MODE==2) v = (row==col?3.f:0.f) - v;
      PD[row][col] = pack_hl(v);
    }
  }
}

// ---------------- kernel 2: Newton-Schulz + triuvec -> vec ----------------
__global__ __launch_bounds__(512) void k_ns(const float* __restrict__ pgram,
    const float* __restrict__ psum, float* __restrict__ vecg){
  __shared__ float Af[64][68];
  __shared__ unsigned int PA[64][68];
  __shared__ unsigned int PT[64][68];
  __shared__ unsigned int PY[64][68];
  __shared__ unsigned int PZ[64][68];
  __shared__ float meanl[64];
  __shared__ float snorm;
  int b = blockIdx.x, tid = threadIdx.x;
  int lane = tid & 63, wv = tid >> 6, rp = wv & 3, ch = wv >> 2;
  const float* pc0 = pgram + ((size_t)b*8) * (NATT*NATT);
  if (tid < 64){
    const float* ps = psum + (size_t)b*512;
    float s = 0.f;
#pragma unroll
    for (int k=0;k<8;k++) s += ps[64*k + tid];
    meanl[tid] = s * (1.f/1024.f);
  }
  __syncthreads();
  for (int e=tid; e<4096; e+=512){
    int i = e>>6, j = e&63;
    float s = 0.f;
#pragma unroll
    for (int k=0;k<8;k++) s += pc0[4096*k + e];
    Af[i][j] = s * (1.f/1024.f) - meanl[i]*meanl[j];
  }
  __syncthreads();
  if (tid < 64){
    float s = Af[tid][tid];
#pragma unroll
    for (int off=32; off; off>>=1) s += __shfl_down(s, off);
    if (tid==0) snorm = s;
  }
  __syncthreads();
  float normA = snorm;
  float inv = 1.f/normA;
  for (int e=tid; e<4096; e+=512){
    int i = e>>6, j = e&63;
    float an = Af[i][j]*inv;
    float t  = 0.5f*((i==j?3.f:0.f) - an);
    unsigned int pt = pack_hl(t);
    PA[i][j] = pack_hl(an);
    PT[i][j] = pt;
    PZ[i][j] = pt;
  }
  __syncthreads();

  f32x4 accY[2], accZ[2];
  wave_mm(PA, PT, lane, rp, ch, accY);
  store_packed<0>(PY, accY, lane, rp, ch);
  __syncthreads();

  for (int it=0; it<3; ++it){
    wave_mm(PZ, PY, lane, rp, ch, accY);
    store_packed<1>(PT, accY, lane, rp, ch);
    __syncthreads();
    wave_mm(PY, PT, lane, rp, ch, accY);
    wave_mm(PT, PZ, lane, rp, ch, accZ);
    __syncthreads();
    store_packed<0>(PY, accY, lane, rp, ch);
    store_packed<0>(PZ, accZ, lane, rp, ch);
    __syncthreads();
  }
  wave_mm(PZ, PY, lane, rp, ch, accY);
  store_packed<2>(PT, accY, lane, rp, ch);
  __syncthreads();
  wave_mm(PY, PT, lane, rp, ch, accY);
  float scl = 0.5f * sqrtf(normA);
  {
    int i15 = lane & 15, q = lane >> 4;
#pragma unroll
    for (int ct=0; ct<2; ct++){
      int col = ch*32 + ct*16 + i15;
#pragma unroll
      for (int r=0; r<4; r++){
        int row = rp*16 + q*4 + r;
        Af[row][col] = accY[ct][r]*scl;
      }
    }
  }
  __syncthreads();
  float* vp = vecg + (size_t)b*TRI;
  for (int e=tid; e<4096; e+=512){
    int i = e>>6, j = e&63;
    if (j >= i){
      int t0 = (i*(129 - i)) >> 1;
      vp[t0 + j - i] = Af[i][j];
    }
  }
}

// ---------------- kernel 3: FC + sigmoid ----------------
__global__ __launch_bounds__(512) void k_fc(const float* __restrict__ vecg,
    const float* __restrict__ fcw, const float* __restrict__ fcb,
    float* __restrict__ gate){
  __shared__ float fwL[16][2080];
  __shared__ __align__(16) float vecL[2080];
  int bg = blockIdx.x >> 4, pg = blockIdx.x & 15;
  int tid = threadIdx.x;
  for (int i=tid; i<8320; i+=512){
    int row = i/520, c4 = i - row*520;
    *(float4*)&fwL[row][c4<<2] = *(const float4*)(fcw + (size_t)(pg*16+row)*TRI + (c4<<2));
  }
  int p = tid >> 5, s = tid & 31;
  int base = s*65;
  float bias = fcb[pg*16 + p];
  for (int bi=0; bi<16; ++bi){
    int b = bg*16 + bi;
    __syncthreads();
    for (int i=tid; i<520; i+=512)
      *(float4*)&vecL[i<<2] = *(const float4*)(vecg + (size_t)b*TRI + (i<<2));
    __syncthreads();
    float acc = 0.f;
#pragma unroll 13
    for (int m=0; m<65; ++m)
      acc = fmaf(fwL[p][base+m], vecL[base+m], acc);
    acc += __shfl_down(acc, 16, 32);
    acc += __shfl_down(acc, 8, 32);
    acc += __shfl_down(acc, 4, 32);
    acc += __shfl_down(acc, 2, 32);
    acc += __shfl_down(acc, 1, 32);
    if (s==0)
      gate[(size_t)b*PLANES + pg*16 + p] = 1.f/(1.f + expf(-(acc + bias)));
  }
}

// ---------------- kernel 4: out = x * gate[b,c] ----------------
__global__ __launch_bounds__(256) void k_gate_mul(const float* __restrict__ x,
    const float* __restrict__ gate, float* __restrict__ out){
  size_t base = (size_t)blockIdx.x*256 + threadIdx.x;
#pragma unroll
  for (int k=0;k<8;k++){
    size_t i4 = base + (size_t)k*1048576;
    size_t e  = i4 << 2;
    int bc = (int)(e >> 10);
    float g = gate[bc];
    float4 v = *(const float4*)(x + e);
    v.x *= g; v.y *= g; v.z *= g; v.w *= g;
    *(float4*)(out + e) = v;
  }
}

extern "C" void kernel_launch(void* const* d_in, const int* in_sizes, int n_in,
                              void* d_out, int out_size, void* d_ws, size_t ws_size,
                              hipStream_t stream) {
  const float* x    = (const float*)d_in[0];
  const float* cw   = (const float*)d_in[1];
  const float* gam  = (const float*)d_in[2];
  const float* bet  = (const float*)d_in[3];
  const float* mu   = (const float*)d_in[4];
  const float* var  = (const float*)d_in[5];
  const float* fcw  = (const float*)d_in[6];
  const float* fcb  = (const float*)d_in[7];
  float* out = (float*)d_out;
  float* ws  = (float*)d_ws;

  unsigned int* wpack = (unsigned int*)(ws + WPACK_OFF);
  float* gate  = ws + GATE_OFF;
  float* psum  = ws + PSUM_OFF;
  float* pgram = ws + PGRAM_OFF;
  float* vecg  = ws + VEC_OFF;

  k_pack_w<<<1, 256, 0, stream>>>(cw, wpack);
  k_conv_gram<<<BATCH*8, 512, 0, stream>>>(x, wpack, gam, bet, mu, var, pgram, psum);
  k_ns<<<BATCH, 512, 0, stream>>>(pgram, psum, vecg);
  k_fc<<<128, 512, 0, stream>>>(vecg, fcw, fcb, gate);
  k_gate_mul<<<4096, 256, 0, stream>>>(x, gate, out);
}

// Round 6
// 141.466 us; speedup vs baseline: 1.8880x; 1.1151x over previous
//
#include <hip/hip_runtime.h>
#include <math.h>

#define BATCH  128
#define CIN    256
#define HWSZ   1024
#define NATT   64
#define TRI    2080
#define PLANES 256

typedef __attribute__((ext_vector_type(8))) short short8v;
typedef __attribute__((ext_vector_type(4))) float f32x4;

// ---------------- workspace layout (float slots) ----------------
static const size_t WPACK_OFF = 0;         // uint [64][256]       16384
static const size_t GATE_OFF  = 16384;     // [128][256]           32768
static const size_t PSUM_OFF  = 49152;     // [1024][64]           65536
static const size_t PGRAM_OFF = 114688;    // [1024][64][64]       4194304
static const size_t VEC_OFF   = 4308992;   // [128][2080]          266240

// ---------------- split-precision helpers ----------------
__device__ __forceinline__ unsigned int pack_hl(float v){
  unsigned int b  = __float_as_uint(v);
  unsigned int hb = b >> 16;                       // truncated bf16 (hi)
  float hif = __uint_as_float(hb << 16);
  float lo  = v - hif;
  unsigned int lb = __float_as_uint(lo) >> 16;
  return hb | (lb << 16);
}

// 8 packed uints -> hi/lo bf16x8 via v_perm (2 ops per dword pair)
__device__ __forceinline__ void unpack8p(const unsigned int* w, short8v& h, short8v& l){
  union { unsigned int u[4]; short8v s; } H, L;
#pragma unroll
  for (int i=0;i<4;i++){
    H.u[i] = __builtin_amdgcn_perm(w[2*i+1], w[2*i], 0x05040100u);
    L.u[i] = __builtin_amdgcn_perm(w[2*i+1], w[2*i], 0x07060302u);
  }
  h = H.s; l = L.s;
}
__device__ __forceinline__ void unpack8v(uint4 a, uint4 b, short8v& h, short8v& l){
  unsigned int w[8] = {a.x,a.y,a.z,a.w,b.x,b.y,b.z,b.w};
  unpack8p(w, h, l);
}

// ---------------- kernel 0: pack conv_w to bf16 hi/lo ----------------
__global__ void k_pack_w(const float* __restrict__ w, unsigned int* __restrict__ wp){
  int idx = blockIdx.x*256 + threadIdx.x;
  if (idx < NATT*CIN) wp[idx] = pack_hl(w[idx]);
}

// ---------------- kernel 1: fused conv+BN+ReLU+gram ----------------
// grid: 128 b x 8 chunks (128 px) = 1024 blocks, 512 threads (8 waves).
// Pipelined: double-buffered xs + register prefetch; ONE barrier per K-step.
__global__ __launch_bounds__(512, 4) void k_conv_gram(
    const float* __restrict__ x, const unsigned int* __restrict__ wpack,
    const float* __restrict__ gam, const float* __restrict__ bet,
    const float* __restrict__ mu,  const float* __restrict__ var,
    float* __restrict__ pgram, float* __restrict__ psum){
  __shared__ unsigned int xs[2][128][36];   // [p][c] transposed, 2-way banks
  __shared__ unsigned int yt[64][132];
  __shared__ float scl[64], shf[64];
  __shared__ float psl[2][64];
  int bid = blockIdx.x;
  int b = bid >> 3, chunk = bid & 7;
  int tid = threadIdx.x;
  int l = tid & 63, w = tid >> 6;
  int i16 = l & 15, q = l >> 4;
  int o0 = (w & 3) * 16, phalf = (w >> 2) * 64;
  if (tid < 64){
    float sc = gam[tid]*rsqrtf(var[tid]+1e-5f);
    scl[tid] = sc; shf[tid] = bet[tid] - mu[tid]*sc;
  }
  const float* xb = x + ((size_t)b*CIN)*HWSZ + chunk*128;
  int cS = tid >> 4;          // staging channel 0..31
  int pS = tid & 15;          // staging pixel base
  f32x4 acc[4];
#pragma unroll
  for (int t=0;t<4;t++) acc[t] = (f32x4){0.f,0.f,0.f,0.f};

  // prologue: stage chunk 0 into buf 0
  float v[8];
#pragma unroll
  for (int j=0;j<8;j++) v[j] = xb[(size_t)cS*HWSZ + pS + 16*j];
#pragma unroll
  for (int j=0;j<8;j++) xs[0][pS+16*j][cS] = pack_hl(v[j]);

  for (int cc=0; cc<8; ++cc){
    int buf = cc & 1;
    __syncthreads();
    // issue next K-step's global loads (land during MFMA below)
    if (cc < 7){
#pragma unroll
      for (int j=0;j<8;j++) v[j] = xb[(size_t)((cc+1)*32+cS)*HWSZ + pS + 16*j];
    }
    // A-frag (weights), L2-hot
    const unsigned int* wp = wpack + (o0+i16)*256 + cc*32 + q*8;
    uint4 a0 = *(const uint4*)wp;
    uint4 a1 = *(const uint4*)(wp+4);
    short8v ah, al; unpack8v(a0,a1,ah,al);
#pragma unroll
    for (int t=0;t<4;t++){
      int p = phalf + t*16 + i16;
      uint4 b0 = *(const uint4*)&xs[buf][p][q*8];
      uint4 b1 = *(const uint4*)&xs[buf][p][q*8+4];
      short8v bh, bl; unpack8v(b0,b1,bh,bl);
      acc[t] = __builtin_amdgcn_mfma_f32_16x16x32_bf16(ah, bh, acc[t],0,0,0);
      acc[t] = __builtin_amdgcn_mfma_f32_16x16x32_bf16(ah, bl, acc[t],0,0,0);
      acc[t] = __builtin_amdgcn_mfma_f32_16x16x32_bf16(al, bh, acc[t],0,0,0);
    }
    // pack + write next buffer (other half of dbuf; barrier at loop top protects)
    if (cc < 7){
#pragma unroll
      for (int j=0;j<8;j++) xs[buf^1][pS+16*j][cS] = pack_hl(v[j]);
    }
  }
  // epilogue: BN + ReLU in regs, pack -> yt; row sums via 16-lane shuffles
  float rs[4] = {0.f,0.f,0.f,0.f};
#pragma unroll
  for (int t=0;t<4;t++){
    int p = phalf + t*16 + i16;
#pragma unroll
    for (int r=0;r<4;r++){
      int o = o0 + q*4 + r;
      float vv = fmaf(acc[t][r], scl[o], shf[o]);
      vv = vv>0.f ? vv : 0.f;
      yt[o][p] = pack_hl(vv);
      rs[r] += vv;
    }
  }
#pragma unroll
  for (int r=0;r<4;r++){
#pragma unroll
    for (int m=1;m<16;m<<=1) rs[r] += __shfl_xor(rs[r], m, 16);
  }
  if (i16 == 0){
#pragma unroll
    for (int r=0;r<4;r++) psl[w>>2][o0 + q*4 + r] = rs[r];
  }
  __syncthreads();
  if (tid < 64) psum[(size_t)bid*64 + tid] = psl[0][tid] + psl[1][tid];
  // gram = Y Y^T over 128 px: wave -> tiles (ti, tj0), (ti, tj0+1)
  {
    f32x4 g0 = (f32x4){0.f,0.f,0.f,0.f}, g1 = g0;
    int ti = w >> 1, tj0 = (w & 1) * 2;
#pragma unroll
    for (int ks=0; ks<4; ks++){
      int k0 = ks*32 + q*8;
      uint4 a0 = *(const uint4*)&yt[ti*16 + i16][k0];
      uint4 a1 = *(const uint4*)&yt[ti*16 + i16][k0+4];
      short8v ah2, al2; unpack8v(a0,a1,ah2,al2);
      uint4 c0v = *(const uint4*)&yt[tj0*16 + i16][k0];
      uint4 c1v = *(const uint4*)&yt[tj0*16 + i16][k0+4];
      short8v bh0, bl0; unpack8v(c0v,c1v,bh0,bl0);
      uint4 d0v = *(const uint4*)&yt[(tj0+1)*16 + i16][k0];
      uint4 d1v = *(const uint4*)&yt[(tj0+1)*16 + i16][k0+4];
      short8v bh1, bl1; unpack8v(d0v,d1v,bh1,bl1);
      g0 = __builtin_amdgcn_mfma_f32_16x16x32_bf16(ah2, bh0, g0,0,0,0);
      g0 = __builtin_amdgcn_mfma_f32_16x16x32_bf16(ah2, bl0, g0,0,0,0);
      g0 = __builtin_amdgcn_mfma_f32_16x16x32_bf16(al2, bh0, g0,0,0,0);
      g1 = __builtin_amdgcn_mfma_f32_16x16x32_bf16(ah2, bh1, g1,0,0,0);
      g1 = __builtin_amdgcn_mfma_f32_16x16x32_bf16(ah2, bl1, g1,0,0,0);
      g1 = __builtin_amdgcn_mfma_f32_16x16x32_bf16(al2, bh1, g1,0,0,0);
    }
    float* pg = pgram + (size_t)bid*4096;
#pragma unroll
    for (int r=0;r<4;r++){
      int i = ti*16 + q*4 + r;
      pg[i*64 + tj0*16     + i16] = g0[r];
      pg[i*64 + (tj0+1)*16 + i16] = g1[r];
    }
  }
}

// P = L @ R for 64x64 packed hi/lo (R symmetric: B-frags read row-wise).
__device__ __forceinline__ void wave_mm(const unsigned int (*PL)[68],
                                        const unsigned int (*PR)[68],
                                        int lane, int rp, int ch, f32x4* acc){
  f32x4 z = {0.f,0.f,0.f,0.f};
  acc[0] = z; acc[1] = z;
  int i15 = lane & 15, q = lane >> 4;
  int row = rp*16 + i15;
#pragma unroll
  for (int s=0; s<2; s++){
    int kbase = s*32 + (q<<3);
    uint4 a0 = *(const uint4*)&PL[row][kbase];
    uint4 a1 = *(const uint4*)&PL[row][kbase+4];
    short8v ah, al; unpack8v(a0,a1,ah,al);
#pragma unroll
    for (int ct=0; ct<2; ct++){
      const unsigned int* bp = &PR[ch*32 + ct*16 + i15][kbase];
      uint4 b0 = *(const uint4*)bp;
      uint4 b1 = *(const uint4*)(bp+4);
      short8v bh, bl; unpack8v(b0,b1,bh,bl);
      acc[ct] = __builtin_amdgcn_mfma_f32_16x16x32_bf16(ah, bh, acc[ct], 0,0,0);
      acc[ct] = __builtin_amdgcn_mfma_f32_16x16x32_bf16(ah, bl, acc[ct], 0,0,0);
      acc[ct] = __builtin_amdgcn_mfma_f32_16x16x32_bf16(al, bh, acc[ct], 0,0,0);
    }
  }
}

template<int MODE>  // 0: pack(v)  1: pack(0.5*(3I-v))  2: pack(3I-v)
__device__ __forceinline__ void store_packed(unsigned int (*PD)[68], const f32x4* acc,
                                             int lane, int rp, int ch){
  int i15 = lane & 15, q = lane >> 4;
#pragma unroll
  for (int ct=0; ct<2; ct++){
    int col = ch*32 + ct*16 + i15;
#pragma unroll
    for (int r=0; r<4; r++){
      int row = rp*16 + q*4 + r;
      float v = acc[ct][r];
      if (MODE==1) v = 0.5f*((row==col?3.f:0.f) - v);
      if (MODE==2) v = (row==col?3.f:0.f) - v;
      PD[row][col] = pack_hl(v);
    }
  }
}

// ---------------- kernel 2: Newton-Schulz + triuvec -> vec ----------------
__global__ __launch_bounds__(512) void k_ns(const float* __restrict__ pgram,
    const float* __restrict__ psum, float* __restrict__ vecg){
  __shared__ float Af[64][68];
  __shared__ unsigned int PA[64][68];
  __shared__ unsigned int PT[64][68];
  __shared__ unsigned int PY[64][68];
  __shared__ unsigned int PZ[64][68];
  __shared__ float meanl[64];
  __shared__ float snorm;
  int b = blockIdx.x, tid = threadIdx.x;
  int lane = tid & 63, wv = tid >> 6, rp = wv & 3, ch = wv >> 2;
  const float* pc0 = pgram + ((size_t)b*8) * (NATT*NATT);
  if (tid < 64){
    const float* ps = psum + (size_t)b*512;
    float s = 0.f;
#pragma unroll
    for (int k=0;k<8;k++) s += ps[64*k + tid];
    meanl[tid] = s * (1.f/1024.f);
  }
  __syncthreads();
  for (int e=tid; e<4096; e+=512){
    int i = e>>6, j = e&63;
    float s = 0.f;
#pragma unroll
    for (int k=0;k<8;k++) s += pc0[4096*k + e];
    Af[i][j] = s * (1.f/1024.f) - meanl[i]*meanl[j];
  }
  __syncthreads();
  if (tid < 64){
    float s = Af[tid][tid];
#pragma unroll
    for (int off=32; off; off>>=1) s += __shfl_down(s, off);
    if (tid==0) snorm = s;
  }
  __syncthreads();
  float normA = snorm;
  float inv = 1.f/normA;
  for (int e=tid; e<4096; e+=512){
    int i = e>>6, j = e&63;
    float an = Af[i][j]*inv;
    float t  = 0.5f*((i==j?3.f:0.f) - an);
    unsigned int pt = pack_hl(t);
    PA[i][j] = pack_hl(an);
    PT[i][j] = pt;
    PZ[i][j] = pt;
  }
  __syncthreads();

  f32x4 accY[2], accZ[2];
  wave_mm(PA, PT, lane, rp, ch, accY);
  store_packed<0>(PY, accY, lane, rp, ch);
  __syncthreads();

  for (int it=0; it<3; ++it){
    wave_mm(PZ, PY, lane, rp, ch, accY);
    store_packed<1>(PT, accY, lane, rp, ch);
    __syncthreads();
    wave_mm(PY, PT, lane, rp, ch, accY);
    wave_mm(PT, PZ, lane, rp, ch, accZ);
    __syncthreads();
    store_packed<0>(PY, accY, lane, rp, ch);
    store_packed<0>(PZ, accZ, lane, rp, ch);
    __syncthreads();
  }
  wave_mm(PZ, PY, lane, rp, ch, accY);
  store_packed<2>(PT, accY, lane, rp, ch);
  __syncthreads();
  wave_mm(PY, PT, lane, rp, ch, accY);
  float scl = 0.5f * sqrtf(normA);
  {
    int i15 = lane & 15, q = lane >> 4;
#pragma unroll
    for (int ct=0; ct<2; ct++){
      int col = ch*32 + ct*16 + i15;
#pragma unroll
      for (int r=0; r<4; r++){
        int row = rp*16 + q*4 + r;
        Af[row][col] = accY[ct][r]*scl;
      }
    }
  }
  __syncthreads();
  float* vp = vecg + (size_t)b*TRI;
  for (int e=tid; e<4096; e+=512){
    int i = e>>6, j = e&63;
    if (j >= i){
      int t0 = (i*(129 - i)) >> 1;
      vp[t0 + j - i] = Af[i][j];
    }
  }
}

// ---------------- kernel 3: FC + sigmoid ----------------
__global__ __launch_bounds__(512) void k_fc(const float* __restrict__ vecg,
    const float* __restrict__ fcw, const float* __restrict__ fcb,
    float* __restrict__ gate){
  __shared__ float fwL[16][2080];
  __shared__ __align__(16) float vecL[2080];
  int bg = blockIdx.x >> 4, pg = blockIdx.x & 15;
  int tid = threadIdx.x;
  for (int i=tid; i<8320; i+=512){
    int row = i/520, c4 = i - row*520;
    *(float4*)&fwL[row][c4<<2] = *(const float4*)(fcw + (size_t)(pg*16+row)*TRI + (c4<<2));
  }
  int p = tid >> 5, s = tid & 31;
  int base = s*65;
  float bias = fcb[pg*16 + p];
  for (int bi=0; bi<16; ++bi){
    int b = bg*16 + bi;
    __syncthreads();
    for (int i=tid; i<520; i+=512)
      *(float4*)&vecL[i<<2] = *(const float4*)(vecg + (size_t)b*TRI + (i<<2));
    __syncthreads();
    float acc = 0.f;
#pragma unroll 13
    for (int m=0; m<65; ++m)
      acc = fmaf(fwL[p][base+m], vecL[base+m], acc);
    acc += __shfl_down(acc, 16, 32);
    acc += __shfl_down(acc, 8, 32);
    acc += __shfl_down(acc, 4, 32);
    acc += __shfl_down(acc, 2, 32);
    acc += __shfl_down(acc, 1, 32);
    if (s==0)
      gate[(size_t)b*PLANES + pg*16 + p] = 1.f/(1.f + expf(-(acc + bias)));
  }
}

// ---------------- kernel 4: out = x * gate[b,c] ----------------
__global__ __launch_bounds__(256) void k_gate_mul(const float* __restrict__ x,
    const float* __restrict__ gate, float* __restrict__ out){
  size_t base = (size_t)blockIdx.x*256 + threadIdx.x;
#pragma unroll
  for (int k=0;k<8;k++){
    size_t i4 = base + (size_t)k*1048576;
    size_t e  = i4 << 2;
    int bc = (int)(e >> 10);
    float g = gate[bc];
    float4 v = *(const float4*)(x + e);
    v.x *= g; v.y *= g; v.z *= g; v.w *= g;
    *(float4*)(out + e) = v;
  }
}

extern "C" void kernel_launch(void* const* d_in, const int* in_sizes, int n_in,
                              void* d_out, int out_size, void* d_ws, size_t ws_size,
                              hipStream_t stream) {
  const float* x    = (const float*)d_in[0];
  const float* cw   = (const float*)d_in[1];
  const float* gam  = (const float*)d_in[2];
  const float* bet  = (const float*)d_in[3];
  const float* mu   = (const float*)d_in[4];
  const float* var  = (const float*)d_in[5];
  const float* fcw  = (const float*)d_in[6];
  const float* fcb  = (const float*)d_in[7];
  float* out = (float*)d_out;
  float* ws  = (float*)d_ws;

  unsigned int* wpack = (unsigned int*)(ws + WPACK_OFF);
  float* gate  = ws + GATE_OFF;
  float* psum  = ws + PSUM_OFF;
  float* pgram = ws + PGRAM_OFF;
  float* vecg  = ws + VEC_OFF;

  k_pack_w<<<64, 256, 0, stream>>>(cw, wpack);
  k_conv_gram<<<BATCH*8, 512, 0, stream>>>(x, wpack, gam, bet, mu, var, pgram, psum);
  k_ns<<<BATCH, 512, 0, stream>>>(pgram, psum, vecg);
  k_fc<<<128, 512, 0, stream>>>(vecg, fcw, fcb, gate);
  k_gate_mul<<<4096, 256, 0, stream>>>(x, gate, out);
}